// Round 1
// baseline (3600.955 us; speedup 1.0000x reference)
//
#include <hip/hip_runtime.h>

typedef unsigned short u16;
typedef unsigned int u32;
typedef __attribute__((ext_vector_type(8))) short short8;
typedef __attribute__((ext_vector_type(4))) float f32x4;

constexpr int HD = 2048;     // hidden / K
constexpr int NR = 4096;     // rows B*S
constexpr int VO = 128000;   // vocab
constexpr int BM = 128, BN = 128, BK = 32;
constexpr int NVB = VO / BN; // 1000 vocab blocks
constexpr int NMB = NR / BM; // 32 row blocks

// ws layout (bytes)
constexpr size_t OFF_XB   = 0;                         // 4096*2048*2 = 16,777,216
constexpr size_t OFF_PMAX = 16777216;                  // 1000*4096*4 = 16,384,000
constexpr size_t OFF_PSUM = OFF_PMAX + 16384000;
constexpr size_t OFF_LSE  = OFF_PSUM + 16384000;
constexpr size_t OFF_TL   = OFF_LSE + (size_t)NR * 4;

// XOR swizzle: moves 16B chunks; bank-spreads 64B-strided b128 reads.
__device__ __forceinline__ unsigned swz16(unsigned a) {
  return a ^ (((a >> 7) & 3u) << 4);
}

// ---------------- x f32 -> bf16 ----------------
__global__ __launch_bounds__(256) void cvt_x_kernel(const float* __restrict__ x,
                                                    u16* __restrict__ xb) {
  int i = blockIdx.x * 256 + threadIdx.x;          // one float4 per thread
  float4 v = reinterpret_cast<const float4*>(x)[i];
  union { __bf16 b[4]; unsigned long long ll; } p;
  p.b[0] = (__bf16)v.x; p.b[1] = (__bf16)v.y;
  p.b[2] = (__bf16)v.z; p.b[3] = (__bf16)v.w;
  reinterpret_cast<unsigned long long*>(xb)[i] = p.ll;
}

// ---------------- main fused GEMM + softmax partials ----------------
__global__ __launch_bounds__(256) void gemm_partials(
    const u16* __restrict__ xb, const float* __restrict__ W,
    float* __restrict__ pmax, float* __restrict__ psum) {
  __shared__ uint4 smem[1024];               // A bytes [0,8192), B bytes [8192,16384)
  __shared__ float smax[BM][2];
  __shared__ float ssum[BM][2];
  char* Ab = reinterpret_cast<char*>(smem);
  char* Bb = Ab + 8192;

  const int tid = threadIdx.x;
  const int w = tid >> 6;
  const int l = tid & 63;
  const int wr = w >> 1, wc = w & 1;

  // XCD-bijective swizzle: 32000 blocks = 8 * 4000; vocab-major within XCD
  const int bid = blockIdx.x;
  const int s = (bid & 7) * (NMB * NVB / 8) + (bid >> 3);
  const int mb = s & (NMB - 1);
  const int vb = s >> 5;                     // NMB == 32
  const int rowbase = mb * BM;
  const int vbase = vb * BN;

  // A staging: global_load_lds writes linear (base + lane*16); pre-swizzle the SOURCE
  const u16* aSrc[2];
  unsigned aBase[2];
#pragma unroll
  for (int i = 0; i < 2; ++i) {
    unsigned lin = (unsigned)w * 2048u + (unsigned)i * 1024u + (unsigned)l * 16u;
    unsigned sb = swz16(lin);
    unsigned r = sb >> 6;                    // row in [0,128): 64B per row (32 bf16)
    unsigned c = (sb >> 1) & 31u;            // col, multiple of 8
    aSrc[i] = xb + (size_t)(rowbase + (int)r) * HD + c;
    aBase[i] = (unsigned)w * 2048u + (unsigned)i * 1024u;  // wave-uniform LDS base
  }

  // B staging (reg-stage f32->bf16): lane-linear ds_write, swizzle-permuted source
  const float* bSrc[2];
  unsigned bLin[2];
#pragma unroll
  for (int i = 0; i < 2; ++i) {
    unsigned lin = (unsigned)i * 4096u + (unsigned)tid * 16u;
    unsigned sb = swz16(lin);
    unsigned n = sb >> 6;
    unsigned k = (sb >> 1) & 31u;
    bSrc[i] = W + (size_t)(vbase + (int)n) * HD + k;
    bLin[i] = lin;
  }

  // fragment LDS byte offsets (swizzled reads)
  const unsigned q = (unsigned)(l >> 4);
  unsigned aOff[4], bOff[4];
#pragma unroll
  for (int m = 0; m < 4; ++m) {
    unsigned R = (unsigned)(wr * 64 + m * 16 + (l & 15));
    aOff[m] = swz16(R * 64u + q * 16u);
    R = (unsigned)(wc * 64 + m * 16 + (l & 15));
    bOff[m] = swz16(R * 64u + q * 16u);
  }

  f32x4 acc[4][4];
#pragma unroll
  for (int m = 0; m < 4; ++m)
#pragma unroll
    for (int n = 0; n < 4; ++n) acc[m][n] = (f32x4)(0.0f);

  for (int kt = 0; kt < HD; kt += BK) {
    // B global loads first (vmcnt will only wait on these before the cvt)
    float4 g0 = *reinterpret_cast<const float4*>(bSrc[0]);
    float4 g1 = *reinterpret_cast<const float4*>(bSrc[0] + 4);
    float4 g2 = *reinterpret_cast<const float4*>(bSrc[1]);
    float4 g3 = *reinterpret_cast<const float4*>(bSrc[1] + 4);
    // A direct-to-LDS (async DMA)
#pragma unroll
    for (int i = 0; i < 2; ++i) {
      __builtin_amdgcn_global_load_lds(
          (const __attribute__((address_space(1))) u32*)aSrc[i],
          (__attribute__((address_space(3))) u32*)(Ab + aBase[i]),
          16, 0, 0);
    }
    // convert (compiler emits v_cvt_pk_bf16_f32 pairs) + b128 LDS writes
    union { __bf16 b[8]; uint4 v; } p0, p1;
    p0.b[0] = (__bf16)g0.x; p0.b[1] = (__bf16)g0.y; p0.b[2] = (__bf16)g0.z; p0.b[3] = (__bf16)g0.w;
    p0.b[4] = (__bf16)g1.x; p0.b[5] = (__bf16)g1.y; p0.b[6] = (__bf16)g1.z; p0.b[7] = (__bf16)g1.w;
    p1.b[0] = (__bf16)g2.x; p1.b[1] = (__bf16)g2.y; p1.b[2] = (__bf16)g2.z; p1.b[3] = (__bf16)g2.w;
    p1.b[4] = (__bf16)g3.x; p1.b[5] = (__bf16)g3.y; p1.b[6] = (__bf16)g3.z; p1.b[7] = (__bf16)g3.w;
    *reinterpret_cast<uint4*>(Bb + bLin[0]) = p0.v;
    *reinterpret_cast<uint4*>(Bb + bLin[1]) = p1.v;
    __syncthreads();

    short8 af[4], bfr[4];
#pragma unroll
    for (int m = 0; m < 4; ++m) af[m] = *reinterpret_cast<const short8*>(Ab + aOff[m]);
#pragma unroll
    for (int n = 0; n < 4; ++n) bfr[n] = *reinterpret_cast<const short8*>(Bb + bOff[n]);
#pragma unroll
    for (int m = 0; m < 4; ++m)
#pragma unroll
      for (int n = 0; n < 4; ++n)
        acc[m][n] = __builtin_amdgcn_mfma_f32_16x16x32_bf16(af[m], bfr[n], acc[m][n], 0, 0, 0);
    __syncthreads();

    aSrc[0] += BK; aSrc[1] += BK;
    bSrc[0] += BK; bSrc[1] += BK;
  }

  // Epilogue: per-row max + sum(exp) over this block's 128 vocab cols.
  // C/D layout: col = lane&15, row = (lane>>4)*4 + reg  [m89-verified]
#pragma unroll
  for (int m = 0; m < 4; ++m) {
#pragma unroll
    for (int j = 0; j < 4; ++j) {
      float v0 = acc[m][0][j], v1 = acc[m][1][j], v2 = acc[m][2][j], v3 = acc[m][3][j];
      float mx = fmaxf(fmaxf(v0, v1), fmaxf(v2, v3));
#pragma unroll
      for (int d = 1; d < 16; d <<= 1) mx = fmaxf(mx, __shfl_xor(mx, d));
      float se = __expf(v0 - mx) + __expf(v1 - mx) + __expf(v2 - mx) + __expf(v3 - mx);
#pragma unroll
      for (int d = 1; d < 16; d <<= 1) se += __shfl_xor(se, d);
      if ((l & 15) == 0) {
        int rloc = wr * 64 + m * 16 + (int)q * 4 + j;
        smax[rloc][wc] = mx;
        ssum[rloc][wc] = se;
      }
    }
  }
  __syncthreads();
  if (tid < BM) {
    float m0 = smax[tid][0], m1 = smax[tid][1];
    float M = fmaxf(m0, m1);
    float S = ssum[tid][0] * __expf(m0 - M) + ssum[tid][1] * __expf(m1 - M);
    size_t o = (size_t)vb * NR + (size_t)(rowbase + tid);   // [vb][row]: coalesced
    pmax[o] = M;
    psum[o] = S;
  }
}

// ---------------- merge partials -> LSE per row ----------------
__global__ __launch_bounds__(256) void row_lse_kernel(const float* __restrict__ pmax,
                                                      const float* __restrict__ psum,
                                                      float* __restrict__ lse) {
  __shared__ float lm[4][64];
  __shared__ float ls[4][64];
  const int rb = blockIdx.x * 64;
  const int rl = threadIdx.x & 63;
  const int g = threadIdx.x >> 6;
  const int r = rb + rl;
  float M = -3.0e38f, S = 0.0f;
  for (int v = g; v < NVB; v += 4) {
    float m = pmax[(size_t)v * NR + r];
    float s = psum[(size_t)v * NR + r];
    float nM = fmaxf(M, m);
    S = S * __expf(M - nM) + s * __expf(m - nM);
    M = nM;
  }
  lm[g][rl] = M; ls[g][rl] = S;
  __syncthreads();
  if (threadIdx.x < 64) {
    float M0 = lm[0][rl], S0 = ls[0][rl];
#pragma unroll
    for (int g2 = 1; g2 < 4; ++g2) {
      float m = lm[g2][rl], s2 = ls[g2][rl];
      float nM = fmaxf(M0, m);
      S0 = S0 * __expf(M0 - nM) + s2 * __expf(m - nM);
      M0 = nM;
    }
    lse[r] = M0 + logf(S0);
  }
}

// ---------------- target logit: dot(x[n], W[y[n]]) in f32 ----------------
__global__ __launch_bounds__(256) void tlogit_kernel(const float* __restrict__ x,
                                                     const int* __restrict__ y,
                                                     const float* __restrict__ W,
                                                     float* __restrict__ tl) {
  const int row = blockIdx.x * 4 + (threadIdx.x >> 6);
  const int l = threadIdx.x & 63;
  const int t = y[row];
  const float4* xr = reinterpret_cast<const float4*>(x + (size_t)row * HD);
  const float4* wr = reinterpret_cast<const float4*>(W + (size_t)t * HD);
  float s = 0.0f;
#pragma unroll
  for (int i = 0; i < HD / 4 / 64; ++i) {
    float4 a = xr[l + i * 64];
    float4 b = wr[l + i * 64];
    s += a.x * b.x + a.y * b.y + a.z * b.z + a.w * b.w;
  }
#pragma unroll
  for (int d = 1; d < 64; d <<= 1) s += __shfl_xor(s, d);
  if (l == 0) tl[row] = s;
}

// ---------------- mean(lse - tlogit) ----------------
__global__ __launch_bounds__(256) void finalize_kernel(const float* __restrict__ lse,
                                                       const float* __restrict__ tl,
                                                       float* __restrict__ out) {
  __shared__ float red[256];
  float s = 0.0f;
  for (int i = threadIdx.x; i < NR; i += 256) s += lse[i] - tl[i];
  red[threadIdx.x] = s;
  __syncthreads();
  for (int d = 128; d > 0; d >>= 1) {
    if ((int)threadIdx.x < d) red[threadIdx.x] += red[threadIdx.x + d];
    __syncthreads();
  }
  if (threadIdx.x == 0) out[0] = red[0] * (1.0f / NR);
}

extern "C" void kernel_launch(void* const* d_in, const int* in_sizes, int n_in,
                              void* d_out, int out_size, void* d_ws, size_t ws_size,
                              hipStream_t stream) {
  const float* x = (const float*)d_in[0];
  const int* y = (const int*)d_in[1];
  const float* W = (const float*)d_in[2];
  float* out = (float*)d_out;
  char* ws = (char*)d_ws;

  u16* xb     = (u16*)(ws + OFF_XB);
  float* pmax = (float*)(ws + OFF_PMAX);
  float* psum = (float*)(ws + OFF_PSUM);
  float* lse  = (float*)(ws + OFF_LSE);
  float* tl   = (float*)(ws + OFF_TL);

  cvt_x_kernel<<<NR * HD / 4 / 256, 256, 0, stream>>>(x, xb);
  gemm_partials<<<NMB * NVB, 256, 0, stream>>>(xb, W, pmax, psum);
  row_lse_kernel<<<NR / 64, 256, 0, stream>>>(pmax, psum, lse);
  tlogit_kernel<<<NR / 4, 256, 0, stream>>>(x, y, W, tl);
  finalize_kernel<<<1, 256, 0, stream>>>(lse, tl, out);
}

// Round 2
// 2962.463 us; speedup vs baseline: 1.2155x; 1.2155x over previous
//
#include <hip/hip_runtime.h>

typedef unsigned short u16;
typedef unsigned int u32;
typedef __attribute__((ext_vector_type(8))) short short8;
typedef __attribute__((ext_vector_type(4))) float f32x4;

constexpr int HD = 2048;     // hidden / K
constexpr int NR = 4096;     // rows B*S
constexpr int VO = 128000;   // vocab

// ---------------- new-path (8-phase 256^2) geometry ----------------
constexpr int NMB8 = NR / 256;    // 16
constexpr int NVB8 = VO / 256;    // 500
// ws layout, new path
constexpr size_t OFF_XB   = 0;                               // 16,777,216
constexpr size_t OFF_WB   = 16777216;                        // 524,288,000
constexpr size_t OFF_P5MX = OFF_WB + 524288000;              // 8,192,000
constexpr size_t OFF_P5SM = OFF_P5MX + 8192000;              // 8,192,000
constexpr size_t OFF_LSE5 = OFF_P5SM + 8192000;              // 16,384
constexpr size_t OFF_TL5  = OFF_LSE5 + 16384;
constexpr size_t NEED_NEW = OFF_TL5 + 16384;                 // ~558 MB

// ws layout, fallback (round-1, 128^2)
constexpr int NVBF = VO / 128;    // 1000
constexpr int NMBF = NR / 128;    // 32
constexpr size_t FB_PMAX = 16777216;
constexpr size_t FB_PSUM = FB_PMAX + 16384000;
constexpr size_t FB_LSE  = FB_PSUM + 16384000;
constexpr size_t FB_TL   = FB_LSE + (size_t)NR * 4;

// st_16x32 swizzle (m201): involution on byte offset within a 16KB half-tile
__device__ __forceinline__ u32 swz8p(u32 a) { return a ^ (((a >> 9) & 1u) << 5); }
// round-1 swizzle (fallback)
__device__ __forceinline__ u32 swz16(u32 a) { return a ^ (((a >> 7) & 3u) << 4); }

// ---------------- x f32 -> bf16 ----------------
__global__ __launch_bounds__(256) void cvt_x_kernel(const float* __restrict__ x,
                                                    u16* __restrict__ xb) {
  int i = blockIdx.x * 256 + threadIdx.x;
  float4 v = reinterpret_cast<const float4*>(x)[i];
  union { __bf16 b[4]; unsigned long long ll; } p;
  p.b[0] = (__bf16)v.x; p.b[1] = (__bf16)v.y;
  p.b[2] = (__bf16)v.z; p.b[3] = (__bf16)v.w;
  reinterpret_cast<unsigned long long*>(xb)[i] = p.ll;
}

// ---------------- W f32 -> bf16 (new path) ----------------
__global__ __launch_bounds__(256) void cvt_w_kernel(const float* __restrict__ W,
                                                    u16* __restrict__ wb) {
  const long total = (long)VO * HD / 8;   // groups of 8 floats
  long i = (long)blockIdx.x * 256 + threadIdx.x;
  const long stride = (long)gridDim.x * 256;
  const float4* W4 = reinterpret_cast<const float4*>(W);
  uint4* wb4 = reinterpret_cast<uint4*>(wb);
  for (; i < total; i += stride) {
    float4 a = W4[i * 2];
    float4 b = W4[i * 2 + 1];
    union { __bf16 h[8]; uint4 v; } p;
    p.h[0] = (__bf16)a.x; p.h[1] = (__bf16)a.y; p.h[2] = (__bf16)a.z; p.h[3] = (__bf16)a.w;
    p.h[4] = (__bf16)b.x; p.h[5] = (__bf16)b.y; p.h[6] = (__bf16)b.z; p.h[7] = (__bf16)b.w;
    wb4[i] = p.v;
  }
}

// ================= 8-phase 256^2 fused GEMM + softmax partials =================
__global__ __launch_bounds__(512, 2) void gemm8(
    const u16* __restrict__ xb, const u16* __restrict__ wb,
    float* __restrict__ pmax, float* __restrict__ psum) {
  // LDS: A [2buf][2half][128][64]bf16 at 0..64K, B same at 64K..128K
  __shared__ uint4 smem4[8192];                 // 128 KB
  __shared__ float smax[256][4];
  __shared__ float ssum[256][4];
  char* Sm = reinterpret_cast<char*>(smem4);

  const int tid = threadIdx.x;
  const int w = tid >> 6, l = tid & 63;
  const int wr = w >> 2, wc = w & 3;
  const int q = l >> 4, r15 = l & 15;

  // XCD-bijective swizzle: 8000 = 8 * 1000; mb fast (W tile L2-reuse)
  const int bid = blockIdx.x;
  const int s = (bid & 7) * 1000 + (bid >> 3);
  const int mb = s & (NMB8 - 1);
  const int vb = s >> 4;
  const int rowbase = mb * 256, vbase = vb * 256;

  // -------- staging precompute: linear LDS dest + inverse-swizzled source --------
  const u16* aS[2][2];
  const u16* bS[2][2];
  u32 aL[2][2], bL[2][2];
#pragma unroll
  for (int h = 0; h < 2; ++h)
#pragma unroll
    for (int i = 0; i < 2; ++i) {
      u32 lin = (u32)i * 8192u + (u32)w * 1024u + (u32)l * 16u;  // byte within 16KB half
      u32 qq = swz8p(lin);
      u32 row = qq >> 7, cb = qq & 127u;
      aS[h][i] = xb + (size_t)(rowbase + h * 128 + (int)row) * HD + (cb >> 1);
      bS[h][i] = wb + (size_t)(vbase + h * 128 + (int)row) * HD + (cb >> 1);
      aL[h][i] = (u32)(h * 16384 + i * 8192 + w * 1024);
      bL[h][i] = (u32)(65536 + h * 16384 + i * 8192 + w * 1024);
    }

  auto stA = [&](int sbuf, int h, int t) {
#pragma unroll
    for (int i = 0; i < 2; ++i)
      __builtin_amdgcn_global_load_lds(
          (const __attribute__((address_space(1))) u32*)(aS[h][i] + (size_t)t * 64),
          (__attribute__((address_space(3))) u32*)(Sm + sbuf * 32768 + aL[h][i]), 16, 0, 0);
  };
  auto stB = [&](int sbuf, int h, int t) {
#pragma unroll
    for (int i = 0; i < 2; ++i)
      __builtin_amdgcn_global_load_lds(
          (const __attribute__((address_space(1))) u32*)(bS[h][i] + (size_t)t * 64),
          (__attribute__((address_space(3))) u32*)(Sm + sbuf * 32768 + bL[h][i]), 16, 0, 0);
  };

  // -------- fragment read offsets (swizzled) --------
  u32 aO[4][2], bO[2][2];
#pragma unroll
  for (int jj = 0; jj < 4; ++jj)
#pragma unroll
    for (int kk = 0; kk < 2; ++kk)
      aO[jj][kk] = swz8p(((u32)(wr * 64 + jj * 16 + r15) << 7) | (u32)(kk * 64 + q * 16));
#pragma unroll
  for (int nn = 0; nn < 2; ++nn)
#pragma unroll
    for (int kk = 0; kk < 2; ++kk)
      bO[nn][kk] = 65536u + swz8p(((u32)(wc * 32 + nn * 16 + r15) << 7) | (u32)(kk * 64 + q * 16));

  short8 aF[4][2], bF[2][2];
  f32x4 acc[8][4];
#pragma unroll
  for (int m = 0; m < 8; ++m)
#pragma unroll
    for (int n = 0; n < 4; ++n) acc[m][n] = (f32x4)(0.0f);

  auto rdA = [&](const char* Sb, int mh) {
#pragma unroll
    for (int jj = 0; jj < 4; ++jj)
#pragma unroll
      for (int kk = 0; kk < 2; ++kk)
        aF[jj][kk] = *reinterpret_cast<const short8*>(Sb + mh * 16384 + aO[jj][kk]);
  };
  auto rdB = [&](const char* Sb, int nh) {
#pragma unroll
    for (int nn = 0; nn < 2; ++nn)
#pragma unroll
      for (int kk = 0; kk < 2; ++kk)
        bF[nn][kk] = *reinterpret_cast<const short8*>(Sb + nh * 16384 + bO[nn][kk]);
  };

#define BAR8()   __builtin_amdgcn_s_barrier()
#define SCHED8() __builtin_amdgcn_sched_barrier(0)
#define WLG8()   asm volatile("s_waitcnt lgkmcnt(0)" ::: "memory")

  auto mmaq = [&](int mh, int nh) {
    __builtin_amdgcn_s_setprio(1);
#pragma unroll
    for (int jj = 0; jj < 4; ++jj)
#pragma unroll
      for (int nn = 0; nn < 2; ++nn)
#pragma unroll
        for (int kk = 0; kk < 2; ++kk)
          acc[mh * 4 + jj][nh * 2 + nn] = __builtin_amdgcn_mfma_f32_16x16x32_bf16(
              aF[jj][kk], bF[nn][kk], acc[mh * 4 + jj][nh * 2 + nn], 0, 0, 0);
    __builtin_amdgcn_s_setprio(0);
  };

  // -------- prologue: tile0 {A0,B0,B1,A1} + tile1 {A0,B1,A1}; B0(1) staged at 0.0 --------
  stA(0, 0, 0); stB(0, 0, 0); stB(0, 1, 0); stA(0, 1, 0);
  stA(1, 0, 1); stB(1, 1, 1); stA(1, 1, 1);
  asm volatile("s_waitcnt vmcnt(6)" ::: "memory");
  BAR8();
  SCHED8();

  // -------- K-loop: 32 tiles x 4 phases --------
  for (int t = 0; t < 32; ++t) {
    const int buf = t & 1, nbuf = buf ^ 1;
    const char* Sb = Sm + buf * 32768;
    // phase 0: quadrant (0,0) — 12 ds_reads
    rdA(Sb, 0);
    rdB(Sb, 0);
    if (t < 31) stB(nbuf, 0, t + 1);
    asm volatile("s_waitcnt lgkmcnt(8)" ::: "memory");
    BAR8(); WLG8(); SCHED8(); mmaq(0, 0); SCHED8(); BAR8();
    // phase 1: quadrant (0,1) — 4 ds_reads (A0 reused in regs)
    rdB(Sb, 1);
    if (t < 30) stA(buf, 0, t + 2);
    BAR8(); WLG8(); SCHED8(); mmaq(0, 1); SCHED8(); BAR8();
    // phase 2: quadrant (1,1) — 8 ds_reads (B1 reused in regs)
    rdA(Sb, 1);
    if (t < 30) stB(buf, 1, t + 2);
    BAR8(); WLG8(); SCHED8(); mmaq(1, 1); SCHED8(); BAR8();
    // phase 3: quadrant (1,0) — 4 ds_reads (B0 re-read; A1 reused)
    rdB(Sb, 0);
    if (t < 30) stA(buf, 1, t + 2);
    if (t < 30)      asm volatile("s_waitcnt vmcnt(6)" ::: "memory");
    else if (t == 30) asm volatile("s_waitcnt vmcnt(0)" ::: "memory");
    BAR8(); WLG8(); SCHED8(); mmaq(1, 0); SCHED8(); BAR8();
  }
#undef BAR8
#undef SCHED8
#undef WLG8

  // -------- epilogue: per-row max + sum(exp) over this block's 256 vocab cols --------
  // C/D: col = lane&15, row = (lane>>4)*4 + reg
#pragma unroll
  for (int m = 0; m < 8; ++m) {
#pragma unroll
    for (int j = 0; j < 4; ++j) {
      float v0 = acc[m][0][j], v1 = acc[m][1][j], v2 = acc[m][2][j], v3 = acc[m][3][j];
      float mx = fmaxf(fmaxf(v0, v1), fmaxf(v2, v3));
#pragma unroll
      for (int d = 1; d < 16; d <<= 1) mx = fmaxf(mx, __shfl_xor(mx, d));
      float se = __expf(v0 - mx) + __expf(v1 - mx) + __expf(v2 - mx) + __expf(v3 - mx);
#pragma unroll
      for (int d = 1; d < 16; d <<= 1) se += __shfl_xor(se, d);
      if (r15 == 0) {
        int r = (m >> 2) * 128 + wr * 64 + (m & 3) * 16 + q * 4 + j;
        smax[r][wc] = mx;
        ssum[r][wc] = se;
      }
    }
  }
  __syncthreads();
  if (tid < 256) {
    float m0 = smax[tid][0], m1 = smax[tid][1], m2 = smax[tid][2], m3 = smax[tid][3];
    float M = fmaxf(fmaxf(m0, m1), fmaxf(m2, m3));
    float S = ssum[tid][0] * __expf(m0 - M) + ssum[tid][1] * __expf(m1 - M) +
              ssum[tid][2] * __expf(m2 - M) + ssum[tid][3] * __expf(m3 - M);
    size_t o = (size_t)vb * NR + (size_t)(rowbase + tid);
    pmax[o] = M;
    psum[o] = S;
  }
}

// ================= fallback 128^2 GEMM (round-1, proven) =================
__global__ __launch_bounds__(256) void gemm_partials_fb(
    const u16* __restrict__ xb, const float* __restrict__ W,
    float* __restrict__ pmax, float* __restrict__ psum) {
  __shared__ uint4 smem[1024];
  __shared__ float smax[128][2];
  __shared__ float ssum[128][2];
  char* Ab = reinterpret_cast<char*>(smem);
  char* Bb = Ab + 8192;

  const int tid = threadIdx.x;
  const int w = tid >> 6;
  const int l = tid & 63;
  const int wr = w >> 1, wc = w & 1;

  const int bid = blockIdx.x;
  const int s = (bid & 7) * (NMBF * NVBF / 8) + (bid >> 3);
  const int mb = s & (NMBF - 1);
  const int vb = s >> 5;
  const int rowbase = mb * 128;
  const int vbase = vb * 128;

  const u16* aSrc[2];
  unsigned aBase[2];
#pragma unroll
  for (int i = 0; i < 2; ++i) {
    unsigned lin = (unsigned)w * 2048u + (unsigned)i * 1024u + (unsigned)l * 16u;
    unsigned sb = swz16(lin);
    unsigned r = sb >> 6;
    unsigned c = (sb >> 1) & 31u;
    aSrc[i] = xb + (size_t)(rowbase + (int)r) * HD + c;
    aBase[i] = (unsigned)w * 2048u + (unsigned)i * 1024u;
  }
  const float* bSrc[2];
  unsigned bLin[2];
#pragma unroll
  for (int i = 0; i < 2; ++i) {
    unsigned lin = (unsigned)i * 4096u + (unsigned)tid * 16u;
    unsigned sb = swz16(lin);
    unsigned n = sb >> 6;
    unsigned k = (sb >> 1) & 31u;
    bSrc[i] = W + (size_t)(vbase + (int)n) * HD + k;
    bLin[i] = lin;
  }
  const unsigned q = (unsigned)(l >> 4);
  unsigned aOff[4], bOff[4];
#pragma unroll
  for (int m = 0; m < 4; ++m) {
    unsigned R = (unsigned)(wr * 64 + m * 16 + (l & 15));
    aOff[m] = swz16(R * 64u + q * 16u);
    R = (unsigned)(wc * 64 + m * 16 + (l & 15));
    bOff[m] = swz16(R * 64u + q * 16u);
  }
  f32x4 acc[4][4];
#pragma unroll
  for (int m = 0; m < 4; ++m)
#pragma unroll
    for (int n = 0; n < 4; ++n) acc[m][n] = (f32x4)(0.0f);

  for (int kt = 0; kt < HD; kt += 32) {
    float4 g0 = *reinterpret_cast<const float4*>(bSrc[0]);
    float4 g1 = *reinterpret_cast<const float4*>(bSrc[0] + 4);
    float4 g2 = *reinterpret_cast<const float4*>(bSrc[1]);
    float4 g3 = *reinterpret_cast<const float4*>(bSrc[1] + 4);
#pragma unroll
    for (int i = 0; i < 2; ++i) {
      __builtin_amdgcn_global_load_lds(
          (const __attribute__((address_space(1))) u32*)aSrc[i],
          (__attribute__((address_space(3))) u32*)(Ab + aBase[i]), 16, 0, 0);
    }
    union { __bf16 b[8]; uint4 v; } p0, p1;
    p0.b[0] = (__bf16)g0.x; p0.b[1] = (__bf16)g0.y; p0.b[2] = (__bf16)g0.z; p0.b[3] = (__bf16)g0.w;
    p0.b[4] = (__bf16)g1.x; p0.b[5] = (__bf16)g1.y; p0.b[6] = (__bf16)g1.z; p0.b[7] = (__bf16)g1.w;
    p1.b[0] = (__bf16)g2.x; p1.b[1] = (__bf16)g2.y; p1.b[2] = (__bf16)g2.z; p1.b[3] = (__bf16)g2.w;
    p1.b[4] = (__bf16)g3.x; p1.b[5] = (__bf16)g3.y; p1.b[6] = (__bf16)g3.z; p1.b[7] = (__bf16)g3.w;
    *reinterpret_cast<uint4*>(Bb + bLin[0]) = p0.v;
    *reinterpret_cast<uint4*>(Bb + bLin[1]) = p1.v;
    __syncthreads();

    short8 af[4], bfr[4];
#pragma unroll
    for (int m = 0; m < 4; ++m) af[m] = *reinterpret_cast<const short8*>(Ab + aOff[m]);
#pragma unroll
    for (int n = 0; n < 4; ++n) bfr[n] = *reinterpret_cast<const short8*>(Bb + bOff[n]);
#pragma unroll
    for (int m = 0; m < 4; ++m)
#pragma unroll
      for (int n = 0; n < 4; ++n)
        acc[m][n] = __builtin_amdgcn_mfma_f32_16x16x32_bf16(af[m], bfr[n], acc[m][n], 0, 0, 0);
    __syncthreads();

    aSrc[0] += 32; aSrc[1] += 32;
    bSrc[0] += 32; bSrc[1] += 32;
  }
#pragma unroll
  for (int m = 0; m < 4; ++m) {
#pragma unroll
    for (int j = 0; j < 4; ++j) {
      float v0 = acc[m][0][j], v1 = acc[m][1][j], v2 = acc[m][2][j], v3 = acc[m][3][j];
      float mx = fmaxf(fmaxf(v0, v1), fmaxf(v2, v3));
#pragma unroll
      for (int d = 1; d < 16; d <<= 1) mx = fmaxf(mx, __shfl_xor(mx, d));
      float se = __expf(v0 - mx) + __expf(v1 - mx) + __expf(v2 - mx) + __expf(v3 - mx);
#pragma unroll
      for (int d = 1; d < 16; d <<= 1) se += __shfl_xor(se, d);
      if ((l & 15) == 0) {
        int rloc = wr * 64 + m * 16 + (int)q * 4 + j;
        smax[rloc][wc] = mx;
        ssum[rloc][wc] = se;
      }
    }
  }
  __syncthreads();
  if (tid < 128) {
    float m0 = smax[tid][0], m1 = smax[tid][1];
    float M = fmaxf(m0, m1);
    float S = ssum[tid][0] * __expf(m0 - M) + ssum[tid][1] * __expf(m1 - M);
    size_t o = (size_t)vb * NR + (size_t)(rowbase + tid);
    pmax[o] = M;
    psum[o] = S;
  }
}

// ---------------- merge partials -> LSE per row ----------------
__global__ __launch_bounds__(256) void row_lse_kernel(const float* __restrict__ pmax,
                                                      const float* __restrict__ psum,
                                                      float* __restrict__ lse, int nvb) {
  __shared__ float lm[4][64];
  __shared__ float ls[4][64];
  const int rb = blockIdx.x * 64;
  const int rl = threadIdx.x & 63;
  const int g = threadIdx.x >> 6;
  const int r = rb + rl;
  float M = -3.0e38f, S = 0.0f;
  for (int v = g; v < nvb; v += 4) {
    float m = pmax[(size_t)v * NR + r];
    float s = psum[(size_t)v * NR + r];
    float nM = fmaxf(M, m);
    S = S * __expf(M - nM) + s * __expf(m - nM);
    M = nM;
  }
  lm[g][rl] = M; ls[g][rl] = S;
  __syncthreads();
  if (threadIdx.x < 64) {
    float M0 = lm[0][rl], S0 = ls[0][rl];
#pragma unroll
    for (int g2 = 1; g2 < 4; ++g2) {
      float m = lm[g2][rl], s2 = ls[g2][rl];
      float nM = fmaxf(M0, m);
      S0 = S0 * __expf(M0 - nM) + s2 * __expf(m - nM);
      M0 = nM;
    }
    lse[r] = M0 + logf(S0);
  }
}

// ---------------- target logit: dot(x[n], W[y[n]]) in f32 ----------------
__global__ __launch_bounds__(256) void tlogit_kernel(const float* __restrict__ x,
                                                     const int* __restrict__ y,
                                                     const float* __restrict__ W,
                                                     float* __restrict__ tl) {
  const int row = blockIdx.x * 4 + (threadIdx.x >> 6);
  const int l = threadIdx.x & 63;
  const int t = y[row];
  const float4* xr = reinterpret_cast<const float4*>(x + (size_t)row * HD);
  const float4* wr = reinterpret_cast<const float4*>(W + (size_t)t * HD);
  float s = 0.0f;
#pragma unroll
  for (int i = 0; i < HD / 4 / 64; ++i) {
    float4 a = xr[l + i * 64];
    float4 b = wr[l + i * 64];
    s += a.x * b.x + a.y * b.y + a.z * b.z + a.w * b.w;
  }
#pragma unroll
  for (int d = 1; d < 64; d <<= 1) s += __shfl_xor(s, d);
  if (l == 0) tl[row] = s;
}

// ---------------- mean(lse - tlogit) ----------------
__global__ __launch_bounds__(256) void finalize_kernel(const float* __restrict__ lse,
                                                       const float* __restrict__ tl,
                                                       float* __restrict__ out) {
  __shared__ float red[256];
  float s = 0.0f;
  for (int i = threadIdx.x; i < NR; i += 256) s += lse[i] - tl[i];
  red[threadIdx.x] = s;
  __syncthreads();
  for (int d = 128; d > 0; d >>= 1) {
    if ((int)threadIdx.x < d) red[threadIdx.x] += red[threadIdx.x + d];
    __syncthreads();
  }
  if (threadIdx.x == 0) out[0] = red[0] * (1.0f / NR);
}

extern "C" void kernel_launch(void* const* d_in, const int* in_sizes, int n_in,
                              void* d_out, int out_size, void* d_ws, size_t ws_size,
                              hipStream_t stream) {
  const float* x = (const float*)d_in[0];
  const int* y = (const int*)d_in[1];
  const float* W = (const float*)d_in[2];
  float* out = (float*)d_out;
  char* ws = (char*)d_ws;

  u16* xb = (u16*)(ws + OFF_XB);
  cvt_x_kernel<<<NR * HD / 4 / 256, 256, 0, stream>>>(x, xb);

  if (ws_size >= NEED_NEW) {
    u16* wb     = (u16*)(ws + OFF_WB);
    float* pmax = (float*)(ws + OFF_P5MX);
    float* psum = (float*)(ws + OFF_P5SM);
    float* lse  = (float*)(ws + OFF_LSE5);
    float* tl   = (float*)(ws + OFF_TL5);
    cvt_w_kernel<<<2048, 256, 0, stream>>>(W, wb);
    gemm8<<<NMB8 * NVB8, 512, 0, stream>>>(xb, wb, pmax, psum);
    row_lse_kernel<<<NR / 64, 256, 0, stream>>>(pmax, psum, lse, NVB8);
    tlogit_kernel<<<NR / 4, 256, 0, stream>>>(x, y, W, tl);
    finalize_kernel<<<1, 256, 0, stream>>>(lse, tl, out);
  } else {
    float* pmax = (float*)(ws + FB_PMAX);
    float* psum = (float*)(ws + FB_PSUM);
    float* lse  = (float*)(ws + FB_LSE);
    float* tl   = (float*)(ws + FB_TL);
    gemm_partials_fb<<<NMBF * NVBF, 256, 0, stream>>>(xb, W, pmax, psum);
    row_lse_kernel<<<NR / 64, 256, 0, stream>>>(pmax, psum, lse, NVBF);
    tlogit_kernel<<<NR / 4, 256, 0, stream>>>(x, y, W, tl);
    finalize_kernel<<<1, 256, 0, stream>>>(lse, tl, out);
  }
}

// Round 3
// 2842.041 us; speedup vs baseline: 1.2670x; 1.0424x over previous
//
#include <hip/hip_runtime.h>

typedef unsigned short u16;
typedef unsigned int u32;
typedef __attribute__((ext_vector_type(8))) short short8;
typedef __attribute__((ext_vector_type(4))) float f32x4;

constexpr int HD = 2048;     // hidden / K
constexpr int NR = 4096;     // rows B*S
constexpr int VO = 128000;   // vocab

// ---------------- new-path (8-phase 256^2) geometry ----------------
constexpr int NMB8 = NR / 256;    // 16
constexpr int NVB8 = VO / 256;    // 500
// ws layout, new path
constexpr size_t OFF_XB   = 0;                               // 16,777,216
constexpr size_t OFF_WB   = 16777216;                        // 524,288,000
constexpr size_t OFF_P5MX = OFF_WB + 524288000;              // 8,192,000
constexpr size_t OFF_P5SM = OFF_P5MX + 8192000;              // 8,192,000
constexpr size_t OFF_LSE5 = OFF_P5SM + 8192000;              // 16,384
constexpr size_t OFF_TL5  = OFF_LSE5 + 16384;
constexpr size_t NEED_NEW = OFF_TL5 + 16384;                 // ~558 MB

// ws layout, fallback (round-1, 128^2)
constexpr int NVBF = VO / 128;    // 1000
constexpr int NMBF = NR / 128;    // 32
constexpr size_t FB_PMAX = 16777216;
constexpr size_t FB_PSUM = FB_PMAX + 16384000;
constexpr size_t FB_LSE  = FB_PSUM + 16384000;
constexpr size_t FB_TL   = FB_LSE + (size_t)NR * 4;

// Swizzle for [128][64]bf16 half-tiles (128 B/row = 8 x 16B slots):
// XOR the three low row bits (addr bits 7-9) into the slot index (bits 4-6).
// A fragment ds_read_b128 (16 lanes @ rows R..R+15, same slot) then spreads
// across all 8 bank groups, 2 lanes each -> conflict-free (2-way is free, m136).
// Involution: XOR writes bits 4-6 only, reads bits 7-9 -> self-inverse.
__device__ __forceinline__ u32 swzA(u32 a) { return a ^ (((a >> 7) & 7u) << 4); }
// round-1 swizzle (fallback path)
__device__ __forceinline__ u32 swz16(u32 a) { return a ^ (((a >> 7) & 3u) << 4); }

// ---------------- x f32 -> bf16 ----------------
__global__ __launch_bounds__(256) void cvt_x_kernel(const float* __restrict__ x,
                                                    u16* __restrict__ xb) {
  int i = blockIdx.x * 256 + threadIdx.x;
  float4 v = reinterpret_cast<const float4*>(x)[i];
  union { __bf16 b[4]; unsigned long long ll; } p;
  p.b[0] = (__bf16)v.x; p.b[1] = (__bf16)v.y;
  p.b[2] = (__bf16)v.z; p.b[3] = (__bf16)v.w;
  reinterpret_cast<unsigned long long*>(xb)[i] = p.ll;
}

// ---------------- W f32 -> bf16 (new path) ----------------
__global__ __launch_bounds__(256) void cvt_w_kernel(const float* __restrict__ W,
                                                    u16* __restrict__ wb) {
  const long total = (long)VO * HD / 8;   // groups of 8 floats
  long i = (long)blockIdx.x * 256 + threadIdx.x;
  const long stride = (long)gridDim.x * 256;
  const float4* W4 = reinterpret_cast<const float4*>(W);
  uint4* wb4 = reinterpret_cast<uint4*>(wb);
  for (; i < total; i += stride) {
    float4 a = W4[i * 2];
    float4 b = W4[i * 2 + 1];
    union { __bf16 h[8]; uint4 v; } p;
    p.h[0] = (__bf16)a.x; p.h[1] = (__bf16)a.y; p.h[2] = (__bf16)a.z; p.h[3] = (__bf16)a.w;
    p.h[4] = (__bf16)b.x; p.h[5] = (__bf16)b.y; p.h[6] = (__bf16)b.z; p.h[7] = (__bf16)b.w;
    wb4[i] = p.v;
  }
}

// ================= 8-phase 256^2 fused GEMM + softmax partials =================
__global__ __launch_bounds__(512, 2) void gemm8(
    const u16* __restrict__ xb, const u16* __restrict__ wb,
    float* __restrict__ pmax, float* __restrict__ psum) {
  // LDS: A [2buf][2half][128][64]bf16 at 0..64K, B same at 64K..128K
  __shared__ uint4 smem4[8192];                 // 128 KB
  __shared__ float smax[256][4];
  __shared__ float ssum[256][4];
  char* Sm = reinterpret_cast<char*>(smem4);

  const int tid = threadIdx.x;
  const int w = tid >> 6, l = tid & 63;
  const int wr = w >> 2, wc = w & 3;
  const int q = l >> 4, r15 = l & 15;

  // XCD-bijective swizzle: 8000 = 8 * 1000; mb fast (W tile L2-reuse)
  const int bid = blockIdx.x;
  const int s = (bid & 7) * 1000 + (bid >> 3);
  const int mb = s & (NMB8 - 1);
  const int vb = s >> 4;
  const int rowbase = mb * 256, vbase = vb * 256;

  // -------- staging precompute: linear LDS dest + inverse-swizzled source --------
  const u16* aS[2][2];
  const u16* bS[2][2];
  u32 aL[2][2], bL[2][2];
#pragma unroll
  for (int h = 0; h < 2; ++h)
#pragma unroll
    for (int i = 0; i < 2; ++i) {
      u32 lin = (u32)i * 8192u + (u32)w * 1024u + (u32)l * 16u;  // byte within 16KB half
      u32 qq = swzA(lin);
      u32 row = qq >> 7, cb = qq & 127u;
      aS[h][i] = xb + (size_t)(rowbase + h * 128 + (int)row) * HD + (cb >> 1);
      bS[h][i] = wb + (size_t)(vbase + h * 128 + (int)row) * HD + (cb >> 1);
      aL[h][i] = (u32)(h * 16384 + i * 8192 + w * 1024);
      bL[h][i] = (u32)(65536 + h * 16384 + i * 8192 + w * 1024);
    }

  auto stA = [&](int sbuf, int h, int t) {
#pragma unroll
    for (int i = 0; i < 2; ++i)
      __builtin_amdgcn_global_load_lds(
          (const __attribute__((address_space(1))) u32*)(aS[h][i] + (size_t)t * 64),
          (__attribute__((address_space(3))) u32*)(Sm + sbuf * 32768 + aL[h][i]), 16, 0, 0);
  };
  auto stB = [&](int sbuf, int h, int t) {
#pragma unroll
    for (int i = 0; i < 2; ++i)
      __builtin_amdgcn_global_load_lds(
          (const __attribute__((address_space(1))) u32*)(bS[h][i] + (size_t)t * 64),
          (__attribute__((address_space(3))) u32*)(Sm + sbuf * 32768 + bL[h][i]), 16, 0, 0);
  };

  // -------- fragment read offsets (swizzled) --------
  u32 aO[4][2], bO[2][2];
#pragma unroll
  for (int jj = 0; jj < 4; ++jj)
#pragma unroll
    for (int kk = 0; kk < 2; ++kk)
      aO[jj][kk] = swzA(((u32)(wr * 64 + jj * 16 + r15) << 7) | (u32)(kk * 64 + q * 16));
#pragma unroll
  for (int nn = 0; nn < 2; ++nn)
#pragma unroll
    for (int kk = 0; kk < 2; ++kk)
      bO[nn][kk] = 65536u + swzA(((u32)(wc * 32 + nn * 16 + r15) << 7) | (u32)(kk * 64 + q * 16));

  short8 aF[4][2], bF[2][2];
  f32x4 acc[8][4];
#pragma unroll
  for (int m = 0; m < 8; ++m)
#pragma unroll
    for (int n = 0; n < 4; ++n) acc[m][n] = (f32x4)(0.0f);

  auto rdA = [&](const char* Sb, int mh) {
#pragma unroll
    for (int jj = 0; jj < 4; ++jj)
#pragma unroll
      for (int kk = 0; kk < 2; ++kk)
        aF[jj][kk] = *reinterpret_cast<const short8*>(Sb + mh * 16384 + aO[jj][kk]);
  };
  auto rdB = [&](const char* Sb, int nh) {
#pragma unroll
    for (int nn = 0; nn < 2; ++nn)
#pragma unroll
      for (int kk = 0; kk < 2; ++kk)
        bF[nn][kk] = *reinterpret_cast<const short8*>(Sb + nh * 16384 + bO[nn][kk]);
  };

#define BAR8()   __builtin_amdgcn_s_barrier()
#define SCHED8() __builtin_amdgcn_sched_barrier(0)
#define WLG8()   asm volatile("s_waitcnt lgkmcnt(0)" ::: "memory")

  auto mmaq = [&](int mh, int nh) {
    __builtin_amdgcn_s_setprio(1);
#pragma unroll
    for (int jj = 0; jj < 4; ++jj)
#pragma unroll
      for (int nn = 0; nn < 2; ++nn)
#pragma unroll
        for (int kk = 0; kk < 2; ++kk)
          acc[mh * 4 + jj][nh * 2 + nn] = __builtin_amdgcn_mfma_f32_16x16x32_bf16(
              aF[jj][kk], bF[nn][kk], acc[mh * 4 + jj][nh * 2 + nn], 0, 0, 0);
    __builtin_amdgcn_s_setprio(0);
  };

  // -------- prologue: tile0 {A0,B0,B1,A1} + tile1 {A0,B1,A1}; B0(1) staged at 0.0 --------
  stA(0, 0, 0); stB(0, 0, 0); stB(0, 1, 0); stA(0, 1, 0);
  stA(1, 0, 1); stB(1, 1, 1); stA(1, 1, 1);
  asm volatile("s_waitcnt vmcnt(6)" ::: "memory");
  BAR8();
  SCHED8();

  // -------- K-loop: 32 tiles x 4 phases --------
  for (int t = 0; t < 32; ++t) {
    const int buf = t & 1, nbuf = buf ^ 1;
    const char* Sb = Sm + buf * 32768;
    // phase 0: quadrant (0,0) — 12 ds_reads
    rdA(Sb, 0);
    rdB(Sb, 0);
    if (t < 31) stB(nbuf, 0, t + 1);
    asm volatile("s_waitcnt lgkmcnt(8)" ::: "memory");
    BAR8(); WLG8(); SCHED8(); mmaq(0, 0); SCHED8(); BAR8();
    // phase 1: quadrant (0,1) — 4 ds_reads (A0 reused in regs)
    rdB(Sb, 1);
    if (t < 30) stA(buf, 0, t + 2);
    BAR8(); WLG8(); SCHED8(); mmaq(0, 1); SCHED8(); BAR8();
    // phase 2: quadrant (1,1) — 8 ds_reads (B1 reused in regs)
    rdA(Sb, 1);
    if (t < 30) stB(buf, 1, t + 2);
    BAR8(); WLG8(); SCHED8(); mmaq(1, 1); SCHED8(); BAR8();
    // phase 3: quadrant (1,0) — 4 ds_reads (B0 re-read; A1 reused)
    rdB(Sb, 0);
    if (t < 30) stA(buf, 1, t + 2);
    if (t < 30)      asm volatile("s_waitcnt vmcnt(6)" ::: "memory");
    else if (t == 30) asm volatile("s_waitcnt vmcnt(0)" ::: "memory");
    BAR8(); WLG8(); SCHED8(); mmaq(1, 0); SCHED8(); BAR8();
  }
#undef BAR8
#undef SCHED8
#undef WLG8

  // -------- epilogue: per-row max + sum(exp) over this block's 256 vocab cols --------
  // C/D: col = lane&15, row = (lane>>4)*4 + reg
#pragma unroll
  for (int m = 0; m < 8; ++m) {
#pragma unroll
    for (int j = 0; j < 4; ++j) {
      float v0 = acc[m][0][j], v1 = acc[m][1][j], v2 = acc[m][2][j], v3 = acc[m][3][j];
      float mx = fmaxf(fmaxf(v0, v1), fmaxf(v2, v3));
#pragma unroll
      for (int d = 1; d < 16; d <<= 1) mx = fmaxf(mx, __shfl_xor(mx, d));
      float se = __expf(v0 - mx) + __expf(v1 - mx) + __expf(v2 - mx) + __expf(v3 - mx);
#pragma unroll
      for (int d = 1; d < 16; d <<= 1) se += __shfl_xor(se, d);
      if (r15 == 0) {
        int r = (m >> 2) * 128 + wr * 64 + (m & 3) * 16 + q * 4 + j;
        smax[r][wc] = mx;
        ssum[r][wc] = se;
      }
    }
  }
  __syncthreads();
  if (tid < 256) {
    float m0 = smax[tid][0], m1 = smax[tid][1], m2 = smax[tid][2], m3 = smax[tid][3];
    float M = fmaxf(fmaxf(m0, m1), fmaxf(m2, m3));
    float S = ssum[tid][0] * __expf(m0 - M) + ssum[tid][1] * __expf(m1 - M) +
              ssum[tid][2] * __expf(m2 - M) + ssum[tid][3] * __expf(m3 - M);
    size_t o = (size_t)vb * NR + (size_t)(rowbase + tid);
    pmax[o] = M;
    psum[o] = S;
  }
}

// ================= fallback 128^2 GEMM (round-1, proven) =================
__global__ __launch_bounds__(256) void gemm_partials_fb(
    const u16* __restrict__ xb, const float* __restrict__ W,
    float* __restrict__ pmax, float* __restrict__ psum) {
  __shared__ uint4 smem[1024];
  __shared__ float smax[128][2];
  __shared__ float ssum[128][2];
  char* Ab = reinterpret_cast<char*>(smem);
  char* Bb = Ab + 8192;

  const int tid = threadIdx.x;
  const int w = tid >> 6;
  const int l = tid & 63;
  const int wr = w >> 1, wc = w & 1;

  const int bid = blockIdx.x;
  const int s = (bid & 7) * (NMBF * NVBF / 8) + (bid >> 3);
  const int mb = s & (NMBF - 1);
  const int vb = s >> 5;
  const int rowbase = mb * 128;
  const int vbase = vb * 128;

  const u16* aSrc[2];
  unsigned aBase[2];
#pragma unroll
  for (int i = 0; i < 2; ++i) {
    unsigned lin = (unsigned)w * 2048u + (unsigned)i * 1024u + (unsigned)l * 16u;
    unsigned sb = swz16(lin);
    unsigned r = sb >> 6;
    unsigned c = (sb >> 1) & 31u;
    aSrc[i] = xb + (size_t)(rowbase + (int)r) * HD + c;
    aBase[i] = (unsigned)w * 2048u + (unsigned)i * 1024u;
  }
  const float* bSrc[2];
  unsigned bLin[2];
#pragma unroll
  for (int i = 0; i < 2; ++i) {
    unsigned lin = (unsigned)i * 4096u + (unsigned)tid * 16u;
    unsigned sb = swz16(lin);
    unsigned n = sb >> 6;
    unsigned k = (sb >> 1) & 31u;
    bSrc[i] = W + (size_t)(vbase + (int)n) * HD + k;
    bLin[i] = lin;
  }
  const unsigned q = (unsigned)(l >> 4);
  unsigned aOff[4], bOff[4];
#pragma unroll
  for (int m = 0; m < 4; ++m) {
    unsigned R = (unsigned)(wr * 64 + m * 16 + (l & 15));
    aOff[m] = swz16(R * 64u + q * 16u);
    R = (unsigned)(wc * 64 + m * 16 + (l & 15));
    bOff[m] = swz16(R * 64u + q * 16u);
  }
  f32x4 acc[4][4];
#pragma unroll
  for (int m = 0; m < 4; ++m)
#pragma unroll
    for (int n = 0; n < 4; ++n) acc[m][n] = (f32x4)(0.0f);

  for (int kt = 0; kt < HD; kt += 32) {
    float4 g0 = *reinterpret_cast<const float4*>(bSrc[0]);
    float4 g1 = *reinterpret_cast<const float4*>(bSrc[0] + 4);
    float4 g2 = *reinterpret_cast<const float4*>(bSrc[1]);
    float4 g3 = *reinterpret_cast<const float4*>(bSrc[1] + 4);
#pragma unroll
    for (int i = 0; i < 2; ++i) {
      __builtin_amdgcn_global_load_lds(
          (const __attribute__((address_space(1))) u32*)aSrc[i],
          (__attribute__((address_space(3))) u32*)(Ab + aBase[i]), 16, 0, 0);
    }
    union { __bf16 b[8]; uint4 v; } p0, p1;
    p0.b[0] = (__bf16)g0.x; p0.b[1] = (__bf16)g0.y; p0.b[2] = (__bf16)g0.z; p0.b[3] = (__bf16)g0.w;
    p0.b[4] = (__bf16)g1.x; p0.b[5] = (__bf16)g1.y; p0.b[6] = (__bf16)g1.z; p0.b[7] = (__bf16)g1.w;
    p1.b[0] = (__bf16)g2.x; p1.b[1] = (__bf16)g2.y; p1.b[2] = (__bf16)g2.z; p1.b[3] = (__bf16)g2.w;
    p1.b[4] = (__bf16)g3.x; p1.b[5] = (__bf16)g3.y; p1.b[6] = (__bf16)g3.z; p1.b[7] = (__bf16)g3.w;
    *reinterpret_cast<uint4*>(Bb + bLin[0]) = p0.v;
    *reinterpret_cast<uint4*>(Bb + bLin[1]) = p1.v;
    __syncthreads();

    short8 af[4], bfr[4];
#pragma unroll
    for (int m = 0; m < 4; ++m) af[m] = *reinterpret_cast<const short8*>(Ab + aOff[m]);
#pragma unroll
    for (int n = 0; n < 4; ++n) bfr[n] = *reinterpret_cast<const short8*>(Bb + bOff[n]);
#pragma unroll
    for (int m = 0; m < 4; ++m)
#pragma unroll
      for (int n = 0; n < 4; ++n)
        acc[m][n] = __builtin_amdgcn_mfma_f32_16x16x32_bf16(af[m], bfr[n], acc[m][n], 0, 0, 0);
    __syncthreads();

    aSrc[0] += 32; aSrc[1] += 32;
    bSrc[0] += 32; bSrc[1] += 32;
  }
#pragma unroll
  for (int m = 0; m < 4; ++m) {
#pragma unroll
    for (int j = 0; j < 4; ++j) {
      float v0 = acc[m][0][j], v1 = acc[m][1][j], v2 = acc[m][2][j], v3 = acc[m][3][j];
      float mx = fmaxf(fmaxf(v0, v1), fmaxf(v2, v3));
#pragma unroll
      for (int d = 1; d < 16; d <<= 1) mx = fmaxf(mx, __shfl_xor(mx, d));
      float se = __expf(v0 - mx) + __expf(v1 - mx) + __expf(v2 - mx) + __expf(v3 - mx);
#pragma unroll
      for (int d = 1; d < 16; d <<= 1) se += __shfl_xor(se, d);
      if ((l & 15) == 0) {
        int rloc = wr * 64 + m * 16 + (int)q * 4 + j;
        smax[rloc][wc] = mx;
        ssum[rloc][wc] = se;
      }
    }
  }
  __syncthreads();
  if (tid < 128) {
    float m0 = smax[tid][0], m1 = smax[tid][1];
    float M = fmaxf(m0, m1);
    float S = ssum[tid][0] * __expf(m0 - M) + ssum[tid][1] * __expf(m1 - M);
    size_t o = (size_t)vb * NR + (size_t)(rowbase + tid);
    pmax[o] = M;
    psum[o] = S;
  }
}

// ---------------- merge partials -> LSE per row ----------------
__global__ __launch_bounds__(256) void row_lse_kernel(const float* __restrict__ pmax,
                                                      const float* __restrict__ psum,
                                                      float* __restrict__ lse, int nvb) {
  __shared__ float lm[4][64];
  __shared__ float ls[4][64];
  const int rb = blockIdx.x * 64;
  const int rl = threadIdx.x & 63;
  const int g = threadIdx.x >> 6;
  const int r = rb + rl;
  float M = -3.0e38f, S = 0.0f;
  for (int v = g; v < nvb; v += 4) {
    float m = pmax[(size_t)v * NR + r];
    float s = psum[(size_t)v * NR + r];
    float nM = fmaxf(M, m);
    S = S * __expf(M - nM) + s * __expf(m - nM);
    M = nM;
  }
  lm[g][rl] = M; ls[g][rl] = S;
  __syncthreads();
  if (threadIdx.x < 64) {
    float M0 = lm[0][rl], S0 = ls[0][rl];
#pragma unroll
    for (int g2 = 1; g2 < 4; ++g2) {
      float m = lm[g2][rl], s2 = ls[g2][rl];
      float nM = fmaxf(M0, m);
      S0 = S0 * __expf(M0 - nM) + s2 * __expf(m - nM);
      M0 = nM;
    }
    lse[r] = M0 + logf(S0);
  }
}

// ---------------- target logit: dot(x[n], W[y[n]]) in f32 ----------------
__global__ __launch_bounds__(256) void tlogit_kernel(const float* __restrict__ x,
                                                     const int* __restrict__ y,
                                                     const float* __restrict__ W,
                                                     float* __restrict__ tl) {
  const int row = blockIdx.x * 4 + (threadIdx.x >> 6);
  const int l = threadIdx.x & 63;
  const int t = y[row];
  const float4* xr = reinterpret_cast<const float4*>(x + (size_t)row * HD);
  const float4* wr = reinterpret_cast<const float4*>(W + (size_t)t * HD);
  float s = 0.0f;
#pragma unroll
  for (int i = 0; i < HD / 4 / 64; ++i) {
    float4 a = xr[l + i * 64];
    float4 b = wr[l + i * 64];
    s += a.x * b.x + a.y * b.y + a.z * b.z + a.w * b.w;
  }
#pragma unroll
  for (int d = 1; d < 64; d <<= 1) s += __shfl_xor(s, d);
  if (l == 0) tl[row] = s;
}

// ---------------- mean(lse - tlogit) ----------------
__global__ __launch_bounds__(256) void finalize_kernel(const float* __restrict__ lse,
                                                       const float* __restrict__ tl,
                                                       float* __restrict__ out) {
  __shared__ float red[256];
  float s = 0.0f;
  for (int i = threadIdx.x; i < NR; i += 256) s += lse[i] - tl[i];
  red[threadIdx.x] = s;
  __syncthreads();
  for (int d = 128; d > 0; d >>= 1) {
    if ((int)threadIdx.x < d) red[threadIdx.x] += red[threadIdx.x + d];
    __syncthreads();
  }
  if (threadIdx.x == 0) out[0] = red[0] * (1.0f / NR);
}

extern "C" void kernel_launch(void* const* d_in, const int* in_sizes, int n_in,
                              void* d_out, int out_size, void* d_ws, size_t ws_size,
                              hipStream_t stream) {
  const float* x = (const float*)d_in[0];
  const int* y = (const int*)d_in[1];
  const float* W = (const float*)d_in[2];
  float* out = (float*)d_out;
  char* ws = (char*)d_ws;

  u16* xb = (u16*)(ws + OFF_XB);
  cvt_x_kernel<<<NR * HD / 4 / 256, 256, 0, stream>>>(x, xb);

  if (ws_size >= NEED_NEW) {
    u16* wb     = (u16*)(ws + OFF_WB);
    float* pmax = (float*)(ws + OFF_P5MX);
    float* psum = (float*)(ws + OFF_P5SM);
    float* lse  = (float*)(ws + OFF_LSE5);
    float* tl   = (float*)(ws + OFF_TL5);
    cvt_w_kernel<<<2048, 256, 0, stream>>>(W, wb);
    gemm8<<<NMB8 * NVB8, 512, 0, stream>>>(xb, wb, pmax, psum);
    row_lse_kernel<<<NR / 64, 256, 0, stream>>>(pmax, psum, lse, NVB8);
    tlogit_kernel<<<NR / 4, 256, 0, stream>>>(x, y, W, tl);
    finalize_kernel<<<1, 256, 0, stream>>>(lse, tl, out);
  } else {
    float* pmax = (float*)(ws + FB_PMAX);
    float* psum = (float*)(ws + FB_PSUM);
    float* lse  = (float*)(ws + FB_LSE);
    float* tl   = (float*)(ws + FB_TL);
    gemm_partials_fb<<<NMBF * NVBF, 256, 0, stream>>>(xb, W, pmax, psum);
    row_lse_kernel<<<NR / 64, 256, 0, stream>>>(pmax, psum, lse, NVBF);
    tlogit_kernel<<<NR / 4, 256, 0, stream>>>(x, y, W, tl);
    finalize_kernel<<<1, 256, 0, stream>>>(lse, tl, out);
  }
}

// Round 4
// 2785.905 us; speedup vs baseline: 1.2926x; 1.0202x over previous
//
#include <hip/hip_runtime.h>

typedef unsigned short u16;
typedef unsigned int u32;
typedef __attribute__((ext_vector_type(8))) short short8;
typedef __attribute__((ext_vector_type(4))) float f32x4;

constexpr int HD = 2048;     // hidden / K
constexpr int NR = 4096;     // rows B*S
constexpr int VO = 128000;   // vocab

// ---------------- new-path (skewed 256^2) geometry ----------------
constexpr int NMB8 = NR / 256;    // 16
constexpr int NVB8 = VO / 256;    // 500
// ws layout, new path
constexpr size_t OFF_XB   = 0;                               // 16,777,216
constexpr size_t OFF_WB   = 16777216;                        // 524,288,000
constexpr size_t OFF_P5MX = OFF_WB + 524288000;              // 8,192,000
constexpr size_t OFF_P5SM = OFF_P5MX + 8192000;              // 8,192,000
constexpr size_t OFF_LSE5 = OFF_P5SM + 8192000;              // 16,384
constexpr size_t OFF_TL5  = OFF_LSE5 + 16384;
constexpr size_t NEED_NEW = OFF_TL5 + 16384;                 // ~558 MB

// ws layout, fallback (round-1, 128^2)
constexpr int NVBF = VO / 128;    // 1000
constexpr int NMBF = NR / 128;    // 32
constexpr size_t FB_PMAX = 16777216;
constexpr size_t FB_PSUM = FB_PMAX + 16384000;
constexpr size_t FB_LSE  = FB_PSUM + 16384000;
constexpr size_t FB_TL   = FB_LSE + (size_t)NR * 4;

// Swizzle for [128][64]bf16 half-tiles (128 B/row = 8 x 16B slots):
// XOR the three low row bits (addr bits 7-9) into the slot index (bits 4-6).
// Verified round 3: SQ_LDS_BANK_CONFLICT 2.29e8 -> 0.
__device__ __forceinline__ u32 swzA(u32 a) { return a ^ (((a >> 7) & 7u) << 4); }
// round-1 swizzle (fallback path)
__device__ __forceinline__ u32 swz16(u32 a) { return a ^ (((a >> 7) & 3u) << 4); }

// ---------------- x f32 -> bf16 ----------------
__global__ __launch_bounds__(256) void cvt_x_kernel(const float* __restrict__ x,
                                                    u16* __restrict__ xb) {
  int i = blockIdx.x * 256 + threadIdx.x;
  float4 v = reinterpret_cast<const float4*>(x)[i];
  union { __bf16 b[4]; unsigned long long ll; } p;
  p.b[0] = (__bf16)v.x; p.b[1] = (__bf16)v.y;
  p.b[2] = (__bf16)v.z; p.b[3] = (__bf16)v.w;
  reinterpret_cast<unsigned long long*>(xb)[i] = p.ll;
}

// ---------------- W f32 -> bf16 (new path) ----------------
__global__ __launch_bounds__(256) void cvt_w_kernel(const float* __restrict__ W,
                                                    u16* __restrict__ wb) {
  const long total = (long)VO * HD / 8;   // groups of 8 floats
  long i = (long)blockIdx.x * 256 + threadIdx.x;
  const long stride = (long)gridDim.x * 256;
  const float4* W4 = reinterpret_cast<const float4*>(W);
  uint4* wb4 = reinterpret_cast<uint4*>(wb);
  for (; i < total; i += stride) {
    float4 a = W4[i * 2];
    float4 b = W4[i * 2 + 1];
    union { __bf16 h[8]; uint4 v; } p;
    p.h[0] = (__bf16)a.x; p.h[1] = (__bf16)a.y; p.h[2] = (__bf16)a.z; p.h[3] = (__bf16)a.w;
    p.h[4] = (__bf16)b.x; p.h[5] = (__bf16)b.y; p.h[6] = (__bf16)b.z; p.h[7] = (__bf16)b.w;
    wb4[i] = p.v;
  }
}

// ============ skewed 256^2 fused GEMM + softmax partials ============
// 4 barriers/tile; no barrier between a wave's ds_reads and its MFMA
// (own lgkmcnt(0) only) -> 2 waves/SIMD skew and co-schedule MFMA||LDS.
// Hazards:
//  (a) vmcnt+BAR at tile top: buf(T) fully landed (vmcnt(6) steady / 0 at t=31)
//  (b) BAR after Q0: A0(T) reads retired by all waves -> stA(buf,0,T+2) safe
//  (c) BAR after Q1: B1(T) reads retired -> stB(buf,1,T+2) safe
//  (d) BAR after Q2: A1(T) reads retired -> stA(buf,1,T+2) safe
//  B0-region for T+1 staged right after BAR(a) (T-1's B0 readers retired).
__global__ __launch_bounds__(512, 2) void gemm8(
    const u16* __restrict__ xb, const u16* __restrict__ wb,
    float* __restrict__ pmax, float* __restrict__ psum) {
  __shared__ uint4 smem4[8192];                 // 128 KB: A [0,64K), B [64K,128K)
  __shared__ float smax[256][4];
  __shared__ float ssum[256][4];
  char* Sm = reinterpret_cast<char*>(smem4);

  const int tid = threadIdx.x;
  const int w = tid >> 6, l = tid & 63;
  const int wr = w >> 2, wc = w & 3;
  const int q = l >> 4, r15 = l & 15;

  // XCD-bijective swizzle: 8000 = 8 * 1000; mb fast (W tile L2-reuse)
  const int bid = blockIdx.x;
  const int s = (bid & 7) * 1000 + (bid >> 3);
  const int mb = s & (NMB8 - 1);
  const int vb = s >> 4;
  const int rowbase = mb * 256, vbase = vb * 256;

  // -------- staging precompute: linear LDS dest + inverse-swizzled source --------
  const u16* aS[2][2];
  const u16* bS[2][2];
  u32 aL[2][2], bL[2][2];
#pragma unroll
  for (int h = 0; h < 2; ++h)
#pragma unroll
    for (int i = 0; i < 2; ++i) {
      u32 lin = (u32)i * 8192u + (u32)w * 1024u + (u32)l * 16u;  // byte within 16KB half
      u32 qq = swzA(lin);
      u32 row = qq >> 7, cb = qq & 127u;
      aS[h][i] = xb + (size_t)(rowbase + h * 128 + (int)row) * HD + (cb >> 1);
      bS[h][i] = wb + (size_t)(vbase + h * 128 + (int)row) * HD + (cb >> 1);
      aL[h][i] = (u32)(h * 16384 + i * 8192 + w * 1024);
      bL[h][i] = (u32)(65536 + h * 16384 + i * 8192 + w * 1024);
    }

  auto stA = [&](int sbuf, int h, int t) {
#pragma unroll
    for (int i = 0; i < 2; ++i)
      __builtin_amdgcn_global_load_lds(
          (const __attribute__((address_space(1))) u32*)(aS[h][i] + (size_t)t * 64),
          (__attribute__((address_space(3))) u32*)(Sm + sbuf * 32768 + aL[h][i]), 16, 0, 0);
  };
  auto stB = [&](int sbuf, int h, int t) {
#pragma unroll
    for (int i = 0; i < 2; ++i)
      __builtin_amdgcn_global_load_lds(
          (const __attribute__((address_space(1))) u32*)(bS[h][i] + (size_t)t * 64),
          (__attribute__((address_space(3))) u32*)(Sm + sbuf * 32768 + bL[h][i]), 16, 0, 0);
  };

  // -------- fragment read offsets (swizzled) --------
  u32 aO[4][2], bO[2][2];
#pragma unroll
  for (int jj = 0; jj < 4; ++jj)
#pragma unroll
    for (int kk = 0; kk < 2; ++kk)
      aO[jj][kk] = swzA(((u32)(wr * 64 + jj * 16 + r15) << 7) | (u32)(kk * 64 + q * 16));
#pragma unroll
  for (int nn = 0; nn < 2; ++nn)
#pragma unroll
    for (int kk = 0; kk < 2; ++kk)
      bO[nn][kk] = 65536u + swzA(((u32)(wc * 32 + nn * 16 + r15) << 7) | (u32)(kk * 64 + q * 16));

  short8 aF[4][2], bF[2][2];
  f32x4 acc[8][4];
#pragma unroll
  for (int m = 0; m < 8; ++m)
#pragma unroll
    for (int n = 0; n < 4; ++n) acc[m][n] = (f32x4)(0.0f);

  auto rdA = [&](const char* Sb, int mh) {
#pragma unroll
    for (int jj = 0; jj < 4; ++jj)
#pragma unroll
      for (int kk = 0; kk < 2; ++kk)
        aF[jj][kk] = *reinterpret_cast<const short8*>(Sb + mh * 16384 + aO[jj][kk]);
  };
  auto rdB = [&](const char* Sb, int nh) {
#pragma unroll
    for (int nn = 0; nn < 2; ++nn)
#pragma unroll
      for (int kk = 0; kk < 2; ++kk)
        bF[nn][kk] = *reinterpret_cast<const short8*>(Sb + nh * 16384 + bO[nn][kk]);
  };

#define BAR8()   __builtin_amdgcn_s_barrier()
#define SCHED8() __builtin_amdgcn_sched_barrier(0)
#define WLG8()   asm volatile("s_waitcnt lgkmcnt(0)" ::: "memory")

  auto mmaq = [&](int mh, int nh) {
    __builtin_amdgcn_s_setprio(1);
#pragma unroll
    for (int jj = 0; jj < 4; ++jj)
#pragma unroll
      for (int nn = 0; nn < 2; ++nn)
#pragma unroll
        for (int kk = 0; kk < 2; ++kk)
          acc[mh * 4 + jj][nh * 2 + nn] = __builtin_amdgcn_mfma_f32_16x16x32_bf16(
              aF[jj][kk], bF[nn][kk], acc[mh * 4 + jj][nh * 2 + nn], 0, 0, 0);
    __builtin_amdgcn_s_setprio(0);
  };

  // -------- prologue: tile0 {A0,B0,B1,A1} + tile1 {A0,B1,A1}; B0(1) staged in t=0 --------
  stA(0, 0, 0); stB(0, 0, 0); stB(0, 1, 0); stA(0, 1, 0);
  stA(1, 0, 1); stB(1, 1, 1); stA(1, 1, 1);

  // -------- K-loop: 32 tiles x 4 windows, 4 barriers/tile --------
  for (int t = 0; t < 32; ++t) {
    const int buf = t & 1, nbuf = buf ^ 1;
    const char* Sb = Sm + buf * 32768;
    if (t == 31) asm volatile("s_waitcnt vmcnt(0)" ::: "memory");
    else         asm volatile("s_waitcnt vmcnt(6)" ::: "memory");
    BAR8();                                    // (a) buf(T) landed, visible to all
    // window 0: quadrant (0,0)
    rdA(Sb, 0);
    rdB(Sb, 0);
    if (t < 31) stB(nbuf, 0, t + 1);
    WLG8(); SCHED8(); mmaq(0, 0);
    BAR8();                                    // (b) A0(T) region free
    // window 1: quadrant (0,1) — A0 reused in regs
    rdB(Sb, 1);
    if (t < 30) stA(buf, 0, t + 2);
    WLG8(); SCHED8(); mmaq(0, 1);
    BAR8();                                    // (c) B1(T) region free
    // window 2: quadrant (1,1) — B1 reused in regs
    rdA(Sb, 1);
    if (t < 30) stB(buf, 1, t + 2);
    WLG8(); SCHED8(); mmaq(1, 1);
    BAR8();                                    // (d) A1(T) region free
    // window 3: quadrant (1,0) — B0 re-read; A1 reused
    rdB(Sb, 0);
    if (t < 30) stA(buf, 1, t + 2);
    WLG8(); SCHED8(); mmaq(1, 0);
    // no closing barrier — next tile's vmcnt + BAR(a)
  }
#undef BAR8
#undef SCHED8
#undef WLG8

  // -------- epilogue: per-row max + sum(exp) over this block's 256 vocab cols --------
  // C/D: col = lane&15, row = (lane>>4)*4 + reg
#pragma unroll
  for (int m = 0; m < 8; ++m) {
#pragma unroll
    for (int j = 0; j < 4; ++j) {
      float v0 = acc[m][0][j], v1 = acc[m][1][j], v2 = acc[m][2][j], v3 = acc[m][3][j];
      float mx = fmaxf(fmaxf(v0, v1), fmaxf(v2, v3));
#pragma unroll
      for (int d = 1; d < 16; d <<= 1) mx = fmaxf(mx, __shfl_xor(mx, d));
      float se = __expf(v0 - mx) + __expf(v1 - mx) + __expf(v2 - mx) + __expf(v3 - mx);
#pragma unroll
      for (int d = 1; d < 16; d <<= 1) se += __shfl_xor(se, d);
      if (r15 == 0) {
        int r = (m >> 2) * 128 + wr * 64 + (m & 3) * 16 + q * 4 + j;
        smax[r][wc] = mx;
        ssum[r][wc] = se;
      }
    }
  }
  __syncthreads();
  if (tid < 256) {
    float m0 = smax[tid][0], m1 = smax[tid][1], m2 = smax[tid][2], m3 = smax[tid][3];
    float M = fmaxf(fmaxf(m0, m1), fmaxf(m2, m3));
    float S = ssum[tid][0] * __expf(m0 - M) + ssum[tid][1] * __expf(m1 - M) +
              ssum[tid][2] * __expf(m2 - M) + ssum[tid][3] * __expf(m3 - M);
    size_t o = (size_t)vb * NR + (size_t)(rowbase + tid);
    pmax[o] = M;
    psum[o] = S;
  }
}

// ================= fallback 128^2 GEMM (round-1, proven) =================
__global__ __launch_bounds__(256) void gemm_partials_fb(
    const u16* __restrict__ xb, const float* __restrict__ W,
    float* __restrict__ pmax, float* __restrict__ psum) {
  __shared__ uint4 smem[1024];
  __shared__ float smax[128][2];
  __shared__ float ssum[128][2];
  char* Ab = reinterpret_cast<char*>(smem);
  char* Bb = Ab + 8192;

  const int tid = threadIdx.x;
  const int w = tid >> 6;
  const int l = tid & 63;
  const int wr = w >> 1, wc = w & 1;

  const int bid = blockIdx.x;
  const int s = (bid & 7) * (NMBF * NVBF / 8) + (bid >> 3);
  const int mb = s & (NMBF - 1);
  const int vb = s >> 5;
  const int rowbase = mb * 128;
  const int vbase = vb * 128;

  const u16* aSrc[2];
  unsigned aBase[2];
#pragma unroll
  for (int i = 0; i < 2; ++i) {
    unsigned lin = (unsigned)w * 2048u + (unsigned)i * 1024u + (unsigned)l * 16u;
    unsigned sb = swz16(lin);
    unsigned r = sb >> 6;
    unsigned c = (sb >> 1) & 31u;
    aSrc[i] = xb + (size_t)(rowbase + (int)r) * HD + c;
    aBase[i] = (unsigned)w * 2048u + (unsigned)i * 1024u;
  }
  const float* bSrc[2];
  unsigned bLin[2];
#pragma unroll
  for (int i = 0; i < 2; ++i) {
    unsigned lin = (unsigned)i * 4096u + (unsigned)tid * 16u;
    unsigned sb = swz16(lin);
    unsigned n = sb >> 6;
    unsigned k = (sb >> 1) & 31u;
    bSrc[i] = W + (size_t)(vbase + (int)n) * HD + k;
    bLin[i] = lin;
  }
  const unsigned q = (unsigned)(l >> 4);
  unsigned aOff[4], bOff[4];
#pragma unroll
  for (int m = 0; m < 4; ++m) {
    unsigned R = (unsigned)(wr * 64 + m * 16 + (l & 15));
    aOff[m] = swz16(R * 64u + q * 16u);
    R = (unsigned)(wc * 64 + m * 16 + (l & 15));
    bOff[m] = swz16(R * 64u + q * 16u);
  }
  f32x4 acc[4][4];
#pragma unroll
  for (int m = 0; m < 4; ++m)
#pragma unroll
    for (int n = 0; n < 4; ++n) acc[m][n] = (f32x4)(0.0f);

  for (int kt = 0; kt < HD; kt += 32) {
    float4 g0 = *reinterpret_cast<const float4*>(bSrc[0]);
    float4 g1 = *reinterpret_cast<const float4*>(bSrc[0] + 4);
    float4 g2 = *reinterpret_cast<const float4*>(bSrc[1]);
    float4 g3 = *reinterpret_cast<const float4*>(bSrc[1] + 4);
#pragma unroll
    for (int i = 0; i < 2; ++i) {
      __builtin_amdgcn_global_load_lds(
          (const __attribute__((address_space(1))) u32*)aSrc[i],
          (__attribute__((address_space(3))) u32*)(Ab + aBase[i]), 16, 0, 0);
    }
    union { __bf16 b[8]; uint4 v; } p0, p1;
    p0.b[0] = (__bf16)g0.x; p0.b[1] = (__bf16)g0.y; p0.b[2] = (__bf16)g0.z; p0.b[3] = (__bf16)g0.w;
    p0.b[4] = (__bf16)g1.x; p0.b[5] = (__bf16)g1.y; p0.b[6] = (__bf16)g1.z; p0.b[7] = (__bf16)g1.w;
    p1.b[0] = (__bf16)g2.x; p1.b[1] = (__bf16)g2.y; p1.b[2] = (__bf16)g2.z; p1.b[3] = (__bf16)g2.w;
    p1.b[4] = (__bf16)g3.x; p1.b[5] = (__bf16)g3.y; p1.b[6] = (__bf16)g3.z; p1.b[7] = (__bf16)g3.w;
    *reinterpret_cast<uint4*>(Bb + bLin[0]) = p0.v;
    *reinterpret_cast<uint4*>(Bb + bLin[1]) = p1.v;
    __syncthreads();

    short8 af[4], bfr[4];
#pragma unroll
    for (int m = 0; m < 4; ++m) af[m] = *reinterpret_cast<const short8*>(Ab + aOff[m]);
#pragma unroll
    for (int n = 0; n < 4; ++n) bfr[n] = *reinterpret_cast<const short8*>(Bb + bOff[n]);
#pragma unroll
    for (int m = 0; m < 4; ++m)
#pragma unroll
      for (int n = 0; n < 4; ++n)
        acc[m][n] = __builtin_amdgcn_mfma_f32_16x16x32_bf16(af[m], bfr[n], acc[m][n], 0, 0, 0);
    __syncthreads();

    aSrc[0] += 32; aSrc[1] += 32;
    bSrc[0] += 32; bSrc[1] += 32;
  }
#pragma unroll
  for (int m = 0; m < 4; ++m) {
#pragma unroll
    for (int j = 0; j < 4; ++j) {
      float v0 = acc[m][0][j], v1 = acc[m][1][j], v2 = acc[m][2][j], v3 = acc[m][3][j];
      float mx = fmaxf(fmaxf(v0, v1), fmaxf(v2, v3));
#pragma unroll
      for (int d = 1; d < 16; d <<= 1) mx = fmaxf(mx, __shfl_xor(mx, d));
      float se = __expf(v0 - mx) + __expf(v1 - mx) + __expf(v2 - mx) + __expf(v3 - mx);
#pragma unroll
      for (int d = 1; d < 16; d <<= 1) se += __shfl_xor(se, d);
      if ((l & 15) == 0) {
        int rloc = wr * 64 + m * 16 + (int)q * 4 + j;
        smax[rloc][wc] = mx;
        ssum[rloc][wc] = se;
      }
    }
  }
  __syncthreads();
  if (tid < 128) {
    float m0 = smax[tid][0], m1 = smax[tid][1];
    float M = fmaxf(m0, m1);
    float S = ssum[tid][0] * __expf(m0 - M) + ssum[tid][1] * __expf(m1 - M);
    size_t o = (size_t)vb * NR + (size_t)(rowbase + tid);
    pmax[o] = M;
    psum[o] = S;
  }
}

// ---------------- merge partials -> LSE per row ----------------
__global__ __launch_bounds__(256) void row_lse_kernel(const float* __restrict__ pmax,
                                                      const float* __restrict__ psum,
                                                      float* __restrict__ lse, int nvb) {
  __shared__ float lm[4][64];
  __shared__ float ls[4][64];
  const int rb = blockIdx.x * 64;
  const int rl = threadIdx.x & 63;
  const int g = threadIdx.x >> 6;
  const int r = rb + rl;
  float M = -3.0e38f, S = 0.0f;
  for (int v = g; v < nvb; v += 4) {
    float m = pmax[(size_t)v * NR + r];
    float s = psum[(size_t)v * NR + r];
    float nM = fmaxf(M, m);
    S = S * __expf(M - nM) + s * __expf(m - nM);
    M = nM;
  }
  lm[g][rl] = M; ls[g][rl] = S;
  __syncthreads();
  if (threadIdx.x < 64) {
    float M0 = lm[0][rl], S0 = ls[0][rl];
#pragma unroll
    for (int g2 = 1; g2 < 4; ++g2) {
      float m = lm[g2][rl], s2 = ls[g2][rl];
      float nM = fmaxf(M0, m);
      S0 = S0 * __expf(M0 - nM) + s2 * __expf(m - nM);
      M0 = nM;
    }
    lse[r] = M0 + logf(S0);
  }
}

// ---------------- target logit: dot(x[n], W[y[n]]) in f32 ----------------
__global__ __launch_bounds__(256) void tlogit_kernel(const float* __restrict__ x,
                                                     const int* __restrict__ y,
                                                     const float* __restrict__ W,
                                                     float* __restrict__ tl) {
  const int row = blockIdx.x * 4 + (threadIdx.x >> 6);
  const int l = threadIdx.x & 63;
  const int t = y[row];
  const float4* xr = reinterpret_cast<const float4*>(x + (size_t)row * HD);
  const float4* wr = reinterpret_cast<const float4*>(W + (size_t)t * HD);
  float s = 0.0f;
#pragma unroll
  for (int i = 0; i < HD / 4 / 64; ++i) {
    float4 a = xr[l + i * 64];
    float4 b = wr[l + i * 64];
    s += a.x * b.x + a.y * b.y + a.z * b.z + a.w * b.w;
  }
#pragma unroll
  for (int d = 1; d < 64; d <<= 1) s += __shfl_xor(s, d);
  if (l == 0) tl[row] = s;
}

// ---------------- mean(lse - tlogit) ----------------
__global__ __launch_bounds__(256) void finalize_kernel(const float* __restrict__ lse,
                                                       const float* __restrict__ tl,
                                                       float* __restrict__ out) {
  __shared__ float red[256];
  float s = 0.0f;
  for (int i = threadIdx.x; i < NR; i += 256) s += lse[i] - tl[i];
  red[threadIdx.x] = s;
  __syncthreads();
  for (int d = 128; d > 0; d >>= 1) {
    if ((int)threadIdx.x < d) red[threadIdx.x] += red[threadIdx.x + d];
    __syncthreads();
  }
  if (threadIdx.x == 0) out[0] = red[0] * (1.0f / NR);
}

extern "C" void kernel_launch(void* const* d_in, const int* in_sizes, int n_in,
                              void* d_out, int out_size, void* d_ws, size_t ws_size,
                              hipStream_t stream) {
  const float* x = (const float*)d_in[0];
  const int* y = (const int*)d_in[1];
  const float* W = (const float*)d_in[2];
  float* out = (float*)d_out;
  char* ws = (char*)d_ws;

  u16* xb = (u16*)(ws + OFF_XB);
  cvt_x_kernel<<<NR * HD / 4 / 256, 256, 0, stream>>>(x, xb);

  if (ws_size >= NEED_NEW) {
    u16* wb     = (u16*)(ws + OFF_WB);
    float* pmax = (float*)(ws + OFF_P5MX);
    float* psum = (float*)(ws + OFF_P5SM);
    float* lse  = (float*)(ws + OFF_LSE5);
    float* tl   = (float*)(ws + OFF_TL5);
    cvt_w_kernel<<<2048, 256, 0, stream>>>(W, wb);
    gemm8<<<NMB8 * NVB8, 512, 0, stream>>>(xb, wb, pmax, psum);
    row_lse_kernel<<<NR / 64, 256, 0, stream>>>(pmax, psum, lse, NVB8);
    tlogit_kernel<<<NR / 4, 256, 0, stream>>>(x, y, W, tl);
    finalize_kernel<<<1, 256, 0, stream>>>(lse, tl, out);
  } else {
    float* pmax = (float*)(ws + FB_PMAX);
    float* psum = (float*)(ws + FB_PSUM);
    float* lse  = (float*)(ws + FB_LSE);
    float* tl   = (float*)(ws + FB_TL);
    gemm_partials_fb<<<NMBF * NVBF, 256, 0, stream>>>(xb, W, pmax, psum);
    row_lse_kernel<<<NR / 64, 256, 0, stream>>>(pmax, psum, lse, NVBF);
    tlogit_kernel<<<NR / 4, 256, 0, stream>>>(x, y, W, tl);
    finalize_kernel<<<1, 256, 0, stream>>>(lse, tl, out);
  }
}

// Round 5
// 2246.925 us; speedup vs baseline: 1.6026x; 1.2399x over previous
//
#include <hip/hip_runtime.h>
#include <hip/hip_fp8.h>

typedef unsigned short u16;
typedef unsigned char u8;
typedef unsigned int u32;
typedef long long i64;
typedef __attribute__((ext_vector_type(8))) short short8;
typedef __attribute__((ext_vector_type(4))) float f32x4;

constexpr int HD = 2048;     // hidden / K
constexpr int NR = 4096;     // rows B*S
constexpr int VO = 128000;   // vocab

// ---------------- fp8 path geometry: 256^2 tile, K-tile = 128 ----------------
constexpr int NMB8 = NR / 256;    // 16
constexpr int NVB8 = VO / 256;    // 500
constexpr int NT8  = HD / 128;    // 16 K-tiles
constexpr float XSCALE = 32.0f;        // x pre-scale into e4m3 normal range
constexpr float WSCALE = 16384.0f;     // W pre-scale (U(+-0.022) -> +-362)
constexpr float UNSCALE = 1.0f / (XSCALE * WSCALE);  // applied to acc in epilogue

// ws layout (fp8 path)
constexpr size_t OFF_X8  = 0;                          // 4096*2048   = 8,388,608
constexpr size_t OFF_W8  = 8388608;                    // 128000*2048 = 262,144,000
constexpr size_t OFF_PMX = OFF_W8 + 262144000;         // 500*4096*4  = 8,192,000
constexpr size_t OFF_PSM = OFF_PMX + 8192000;
constexpr size_t OFF_LSE = OFF_PSM + 8192000;          // 16,384
constexpr size_t OFF_TL  = OFF_LSE + 16384;
constexpr size_t NEED_NEW = OFF_TL + 16384;            // ~287 MB

// ws layout, fallback (round-1 bf16 128^2, proven)
constexpr int NVBF = VO / 128;    // 1000
constexpr int NMBF = NR / 128;    // 32
constexpr size_t FB_XB   = 0;
constexpr size_t FB_PMAX = 16777216;
constexpr size_t FB_PSUM = FB_PMAX + 16384000;
constexpr size_t FB_LSE  = FB_PSUM + 16384000;
constexpr size_t FB_TL   = FB_LSE + (size_t)NR * 4;

// Swizzle for [128 rows][128 B] half-tiles (8 x 16B slots/row): XOR low 3 row
// bits (addr bits 7-9) into slot index (bits 4-6). Round-3 verified:
// SQ_LDS_BANK_CONFLICT 2.29e8 -> 0. For fp8 b64 fragment reads each 32-lane
// phase lands exactly 2 lanes/bank (free, m136).
__device__ __forceinline__ u32 swzA(u32 a) { return a ^ (((a >> 7) & 7u) << 4); }
// round-1 swizzle (fallback path)
__device__ __forceinline__ u32 swz16(u32 a) { return a ^ (((a >> 7) & 3u) << 4); }

__device__ __forceinline__ u8 f2e4m3(float f) {
  return (u8)__hip_cvt_float_to_fp8(f, __HIP_SATFINITE, __HIP_E4M3);
}

// ---------------- x f32 -> fp8 (x * 32) ----------------
__global__ __launch_bounds__(256) void cvt_x8_kernel(const float* __restrict__ x,
                                                     u8* __restrict__ x8) {
  const long i = (long)blockIdx.x * 256 + threadIdx.x;   // 16 floats per thread
  const float4* X4 = reinterpret_cast<const float4*>(x) + i * 4;
  union { u8 b[16]; uint4 v; } p;
#pragma unroll
  for (int j = 0; j < 4; ++j) {
    float4 a = X4[j];
    p.b[j * 4 + 0] = f2e4m3(a.x * XSCALE);
    p.b[j * 4 + 1] = f2e4m3(a.y * XSCALE);
    p.b[j * 4 + 2] = f2e4m3(a.z * XSCALE);
    p.b[j * 4 + 3] = f2e4m3(a.w * XSCALE);
  }
  reinterpret_cast<uint4*>(x8)[i] = p.v;
}

// ---------------- W f32 -> fp8 (W * 16384) ----------------
__global__ __launch_bounds__(256) void cvt_w8_kernel(const float* __restrict__ W,
                                                     u8* __restrict__ w8) {
  const long total = (long)VO * HD / 16;   // groups of 16 floats
  long i = (long)blockIdx.x * 256 + threadIdx.x;
  const long stride = (long)gridDim.x * 256;
  for (; i < total; i += stride) {
    const float4* W4 = reinterpret_cast<const float4*>(W) + i * 4;
    union { u8 b[16]; uint4 v; } p;
#pragma unroll
    for (int j = 0; j < 4; ++j) {
      float4 a = W4[j];
      p.b[j * 4 + 0] = f2e4m3(a.x * WSCALE);
      p.b[j * 4 + 1] = f2e4m3(a.y * WSCALE);
      p.b[j * 4 + 2] = f2e4m3(a.z * WSCALE);
      p.b[j * 4 + 3] = f2e4m3(a.w * WSCALE);
    }
    reinterpret_cast<uint4*>(w8)[i] = p.v;
  }
}

// ============ skewed 256^2 fp8 fused GEMM + softmax partials ============
// Same pipeline skeleton as the validated bf16 rounds 2-4 (identical stage-call
// pattern -> identical vmcnt ladder), but elements are fp8: K-tile = 128,
// 16 tiles, half the staged bytes. mfma_f32_16x16x32_fp8_fp8 (bf16 rate).
__global__ __launch_bounds__(512, 2) void gemm8(
    const u8* __restrict__ x8, const u8* __restrict__ w8,
    float* __restrict__ pmax, float* __restrict__ psum) {
  __shared__ uint4 smem4[8192];                 // 128 KB: A [0,64K), B [64K,128K)
  __shared__ float smax[256][4];
  __shared__ float ssum[256][4];
  char* Sm = reinterpret_cast<char*>(smem4);

  const int tid = threadIdx.x;
  const int w = tid >> 6, l = tid & 63;
  const int wr = w >> 2, wc = w & 3;
  const int q = l >> 4, r15 = l & 15;

  // XCD-bijective swizzle: 8000 = 8 * 1000; mb fast (W panel L2-reuse)
  const int bid = blockIdx.x;
  const int s = (bid & 7) * 1000 + (bid >> 3);
  const int mb = s & (NMB8 - 1);
  const int vb = s >> 4;
  const int rowbase = mb * 256, vbase = vb * 256;

  // -------- staging: linear LDS dest + inverse-swizzled source (16B cells) ----
  const u8* aS[2][2];
  const u8* bS[2][2];
  u32 aL[2][2], bL[2][2];
#pragma unroll
  for (int h = 0; h < 2; ++h)
#pragma unroll
    for (int i = 0; i < 2; ++i) {
      u32 lin = (u32)i * 8192u + (u32)w * 1024u + (u32)l * 16u;  // byte in 16KB half
      u32 qq = swzA(lin);
      u32 row = qq >> 7, cb = qq & 127u;      // row in [0,128), byte col in [0,128)
      aS[h][i] = x8 + (size_t)(rowbase + h * 128 + (int)row) * HD + cb;
      bS[h][i] = w8 + (size_t)(vbase + h * 128 + (int)row) * HD + cb;
      aL[h][i] = (u32)(h * 16384 + i * 8192 + w * 1024);
      bL[h][i] = (u32)(65536 + h * 16384 + i * 8192 + w * 1024);
    }

  auto stA = [&](int sbuf, int h, int t) {
#pragma unroll
    for (int i = 0; i < 2; ++i)
      __builtin_amdgcn_global_load_lds(
          (const __attribute__((address_space(1))) u32*)(aS[h][i] + (size_t)t * 128),
          (__attribute__((address_space(3))) u32*)(Sm + sbuf * 32768 + aL[h][i]), 16, 0, 0);
  };
  auto stB = [&](int sbuf, int h, int t) {
#pragma unroll
    for (int i = 0; i < 2; ++i)
      __builtin_amdgcn_global_load_lds(
          (const __attribute__((address_space(1))) u32*)(bS[h][i] + (size_t)t * 128),
          (__attribute__((address_space(3))) u32*)(Sm + sbuf * 32768 + bL[h][i]), 16, 0, 0);
  };

  // -------- fragment read offsets (swizzled): b64, k-step kk in [0,4) --------
  u32 aO[4][4], bO[2][4];
#pragma unroll
  for (int jj = 0; jj < 4; ++jj)
#pragma unroll
    for (int kk = 0; kk < 4; ++kk)
      aO[jj][kk] = swzA(((u32)(wr * 64 + jj * 16 + r15) << 7) | (u32)(kk * 32 + q * 8));
#pragma unroll
  for (int nn = 0; nn < 2; ++nn)
#pragma unroll
    for (int kk = 0; kk < 4; ++kk)
      bO[nn][kk] = 65536u + swzA(((u32)(wc * 32 + nn * 16 + r15) << 7) | (u32)(kk * 32 + q * 8));

  i64 aF[4][4], bF[2][4];
  f32x4 acc[8][4];
#pragma unroll
  for (int m = 0; m < 8; ++m)
#pragma unroll
    for (int n = 0; n < 4; ++n) acc[m][n] = (f32x4)(0.0f);

  auto rdA = [&](const char* Sb, int mh) {
#pragma unroll
    for (int jj = 0; jj < 4; ++jj)
#pragma unroll
      for (int kk = 0; kk < 4; ++kk)
        aF[jj][kk] = *reinterpret_cast<const i64*>(Sb + mh * 16384 + aO[jj][kk]);
  };
  auto rdB = [&](const char* Sb, int nh) {
#pragma unroll
    for (int nn = 0; nn < 2; ++nn)
#pragma unroll
      for (int kk = 0; kk < 4; ++kk)
        bF[nn][kk] = *reinterpret_cast<const i64*>(Sb + nh * 16384 + bO[nn][kk]);
  };

#define BAR8()   __builtin_amdgcn_s_barrier()
#define SCHED8() __builtin_amdgcn_sched_barrier(0)
#define WLG8()   asm volatile("s_waitcnt lgkmcnt(0)" ::: "memory")

  auto mmaq = [&](int mh, int nh) {
    __builtin_amdgcn_s_setprio(1);
#pragma unroll
    for (int jj = 0; jj < 4; ++jj)
#pragma unroll
      for (int nn = 0; nn < 2; ++nn)
#pragma unroll
        for (int kk = 0; kk < 4; ++kk)
          acc[mh * 4 + jj][nh * 2 + nn] = __builtin_amdgcn_mfma_f32_16x16x32_fp8_fp8(
              aF[jj][kk], bF[nn][kk], acc[mh * 4 + jj][nh * 2 + nn], 0, 0, 0);
    __builtin_amdgcn_s_setprio(0);
  };

  // -------- prologue: tile0 {A0,B0,B1,A1} + tile1 {A0,B1,A1}; B0(1) in t=0 ----
  stA(0, 0, 0); stB(0, 0, 0); stB(0, 1, 0); stA(0, 1, 0);
  stA(1, 0, 1); stB(1, 1, 1); stA(1, 1, 1);

  // -------- K-loop: 16 tiles x 4 windows, 4 barriers/tile --------
  for (int t = 0; t < NT8; ++t) {
    const int buf = t & 1, nbuf = buf ^ 1;
    const char* Sb = Sm + buf * 32768;
    if (t == NT8 - 1) asm volatile("s_waitcnt vmcnt(0)" ::: "memory");
    else              asm volatile("s_waitcnt vmcnt(6)" ::: "memory");
    BAR8();                                    // (a) buf(T) landed, visible to all
    // window 0: quadrant (0,0)
    rdA(Sb, 0);
    rdB(Sb, 0);
    if (t < NT8 - 1) stB(nbuf, 0, t + 1);
    WLG8(); SCHED8(); mmaq(0, 0);
    BAR8();                                    // (b) A0(T) region free
    // window 1: quadrant (0,1) — A0 reused in regs
    rdB(Sb, 1);
    if (t < NT8 - 2) stA(buf, 0, t + 2);
    WLG8(); SCHED8(); mmaq(0, 1);
    BAR8();                                    // (c) B1(T) region free
    // window 2: quadrant (1,1) — B1 reused in regs
    rdA(Sb, 1);
    if (t < NT8 - 2) stB(buf, 1, t + 2);
    WLG8(); SCHED8(); mmaq(1, 1);
    BAR8();                                    // (d) A1(T) region free
    // window 3: quadrant (1,0) — B0 re-read; A1 reused
    rdB(Sb, 0);
    if (t < NT8 - 2) stA(buf, 1, t + 2);
    WLG8(); SCHED8(); mmaq(1, 0);
    // no closing barrier — next tile's vmcnt + BAR(a)
  }
#undef BAR8
#undef SCHED8
#undef WLG8

  // -------- epilogue: unscale, per-row max + sum(exp) over 256 vocab cols ----
  // C/D: col = lane&15, row = (lane>>4)*4 + reg  (dtype-independent)
#pragma unroll
  for (int m = 0; m < 8; ++m) {
#pragma unroll
    for (int j = 0; j < 4; ++j) {
      float v0 = acc[m][0][j] * UNSCALE, v1 = acc[m][1][j] * UNSCALE;
      float v2 = acc[m][2][j] * UNSCALE, v3 = acc[m][3][j] * UNSCALE;
      float mx = fmaxf(fmaxf(v0, v1), fmaxf(v2, v3));
#pragma unroll
      for (int d = 1; d < 16; d <<= 1) mx = fmaxf(mx, __shfl_xor(mx, d));
      float se = __expf(v0 - mx) + __expf(v1 - mx) + __expf(v2 - mx) + __expf(v3 - mx);
#pragma unroll
      for (int d = 1; d < 16; d <<= 1) se += __shfl_xor(se, d);
      if (r15 == 0) {
        int r = (m >> 2) * 128 + wr * 64 + (m & 3) * 16 + q * 4 + j;
        smax[r][wc] = mx;
        ssum[r][wc] = se;
      }
    }
  }
  __syncthreads();
  if (tid < 256) {
    float m0 = smax[tid][0], m1 = smax[tid][1], m2 = smax[tid][2], m3 = smax[tid][3];
    float M = fmaxf(fmaxf(m0, m1), fmaxf(m2, m3));
    float S = ssum[tid][0] * __expf(m0 - M) + ssum[tid][1] * __expf(m1 - M) +
              ssum[tid][2] * __expf(m2 - M) + ssum[tid][3] * __expf(m3 - M);
    size_t o = (size_t)vb * NR + (size_t)(rowbase + tid);
    pmax[o] = M;
    psum[o] = S;
  }
}

// ================= fallback path (round-1 bf16, proven) =================
__global__ __launch_bounds__(256) void cvt_x_kernel(const float* __restrict__ x,
                                                    u16* __restrict__ xb) {
  int i = blockIdx.x * 256 + threadIdx.x;
  float4 v = reinterpret_cast<const float4*>(x)[i];
  union { __bf16 b[4]; unsigned long long ll; } p;
  p.b[0] = (__bf16)v.x; p.b[1] = (__bf16)v.y;
  p.b[2] = (__bf16)v.z; p.b[3] = (__bf16)v.w;
  reinterpret_cast<unsigned long long*>(xb)[i] = p.ll;
}

__global__ __launch_bounds__(256) void gemm_partials_fb(
    const u16* __restrict__ xb, const float* __restrict__ W,
    float* __restrict__ pmax, float* __restrict__ psum) {
  __shared__ uint4 smem[1024];
  __shared__ float smax[128][2];
  __shared__ float ssum[128][2];
  char* Ab = reinterpret_cast<char*>(smem);
  char* Bb = Ab + 8192;

  const int tid = threadIdx.x;
  const int w = tid >> 6;
  const int l = tid & 63;
  const int wr = w >> 1, wc = w & 1;

  const int bid = blockIdx.x;
  const int s = (bid & 7) * (NMBF * NVBF / 8) + (bid >> 3);
  const int mb = s & (NMBF - 1);
  const int vb = s >> 5;
  const int rowbase = mb * 128;
  const int vbase = vb * 128;

  const u16* aSrc[2];
  unsigned aBase[2];
#pragma unroll
  for (int i = 0; i < 2; ++i) {
    unsigned lin = (unsigned)w * 2048u + (unsigned)i * 1024u + (unsigned)l * 16u;
    unsigned sb = swz16(lin);
    unsigned r = sb >> 6;
    unsigned c = (sb >> 1) & 31u;
    aSrc[i] = xb + (size_t)(rowbase + (int)r) * HD + c;
    aBase[i] = (unsigned)w * 2048u + (unsigned)i * 1024u;
  }
  const float* bSrc[2];
  unsigned bLin[2];
#pragma unroll
  for (int i = 0; i < 2; ++i) {
    unsigned lin = (unsigned)i * 4096u + (unsigned)tid * 16u;
    unsigned sb = swz16(lin);
    unsigned n = sb >> 6;
    unsigned k = (sb >> 1) & 31u;
    bSrc[i] = W + (size_t)(vbase + (int)n) * HD + k;
    bLin[i] = lin;
  }
  const unsigned q = (unsigned)(l >> 4);
  unsigned aOff[4], bOff[4];
#pragma unroll
  for (int m = 0; m < 4; ++m) {
    unsigned R = (unsigned)(wr * 64 + m * 16 + (l & 15));
    aOff[m] = swz16(R * 64u + q * 16u);
    R = (unsigned)(wc * 64 + m * 16 + (l & 15));
    bOff[m] = swz16(R * 64u + q * 16u);
  }
  f32x4 acc[4][4];
#pragma unroll
  for (int m = 0; m < 4; ++m)
#pragma unroll
    for (int n = 0; n < 4; ++n) acc[m][n] = (f32x4)(0.0f);

  for (int kt = 0; kt < HD; kt += 32) {
    float4 g0 = *reinterpret_cast<const float4*>(bSrc[0]);
    float4 g1 = *reinterpret_cast<const float4*>(bSrc[0] + 4);
    float4 g2 = *reinterpret_cast<const float4*>(bSrc[1]);
    float4 g3 = *reinterpret_cast<const float4*>(bSrc[1] + 4);
#pragma unroll
    for (int i = 0; i < 2; ++i) {
      __builtin_amdgcn_global_load_lds(
          (const __attribute__((address_space(1))) u32*)aSrc[i],
          (__attribute__((address_space(3))) u32*)(Ab + aBase[i]), 16, 0, 0);
    }
    union { __bf16 b[8]; uint4 v; } p0, p1;
    p0.b[0] = (__bf16)g0.x; p0.b[1] = (__bf16)g0.y; p0.b[2] = (__bf16)g0.z; p0.b[3] = (__bf16)g0.w;
    p0.b[4] = (__bf16)g1.x; p0.b[5] = (__bf16)g1.y; p0.b[6] = (__bf16)g1.z; p0.b[7] = (__bf16)g1.w;
    p1.b[0] = (__bf16)g2.x; p1.b[1] = (__bf16)g2.y; p1.b[2] = (__bf16)g2.z; p1.b[3] = (__bf16)g2.w;
    p1.b[4] = (__bf16)g3.x; p1.b[5] = (__bf16)g3.y; p1.b[6] = (__bf16)g3.z; p1.b[7] = (__bf16)g3.w;
    *reinterpret_cast<uint4*>(Bb + bLin[0]) = p0.v;
    *reinterpret_cast<uint4*>(Bb + bLin[1]) = p1.v;
    __syncthreads();

    short8 af[4], bfr[4];
#pragma unroll
    for (int m = 0; m < 4; ++m) af[m] = *reinterpret_cast<const short8*>(Ab + aOff[m]);
#pragma unroll
    for (int n = 0; n < 4; ++n) bfr[n] = *reinterpret_cast<const short8*>(Bb + bOff[n]);
#pragma unroll
    for (int m = 0; m < 4; ++m)
#pragma unroll
      for (int n = 0; n < 4; ++n)
        acc[m][n] = __builtin_amdgcn_mfma_f32_16x16x32_bf16(af[m], bfr[n], acc[m][n], 0, 0, 0);
    __syncthreads();

    aSrc[0] += 32; aSrc[1] += 32;
    bSrc[0] += 32; bSrc[1] += 32;
  }
#pragma unroll
  for (int m = 0; m < 4; ++m) {
#pragma unroll
    for (int j = 0; j < 4; ++j) {
      float v0 = acc[m][0][j], v1 = acc[m][1][j], v2 = acc[m][2][j], v3 = acc[m][3][j];
      float mx = fmaxf(fmaxf(v0, v1), fmaxf(v2, v3));
#pragma unroll
      for (int d = 1; d < 16; d <<= 1) mx = fmaxf(mx, __shfl_xor(mx, d));
      float se = __expf(v0 - mx) + __expf(v1 - mx) + __expf(v2 - mx) + __expf(v3 - mx);
#pragma unroll
      for (int d = 1; d < 16; d <<= 1) se += __shfl_xor(se, d);
      if ((l & 15) == 0) {
        int rloc = wr * 64 + m * 16 + (int)q * 4 + j;
        smax[rloc][wc] = mx;
        ssum[rloc][wc] = se;
      }
    }
  }
  __syncthreads();
  if (tid < 128) {
    float m0 = smax[tid][0], m1 = smax[tid][1];
    float M = fmaxf(m0, m1);
    float S = ssum[tid][0] * __expf(m0 - M) + ssum[tid][1] * __expf(m1 - M);
    size_t o = (size_t)vb * NR + (size_t)(rowbase + tid);
    pmax[o] = M;
    psum[o] = S;
  }
}

// ---------------- merge partials -> LSE per row ----------------
__global__ __launch_bounds__(256) void row_lse_kernel(const float* __restrict__ pmax,
                                                      const float* __restrict__ psum,
                                                      float* __restrict__ lse, int nvb) {
  __shared__ float lm[4][64];
  __shared__ float ls[4][64];
  const int rb = blockIdx.x * 64;
  const int rl = threadIdx.x & 63;
  const int g = threadIdx.x >> 6;
  const int r = rb + rl;
  float M = -3.0e38f, S = 0.0f;
  for (int v = g; v < nvb; v += 4) {
    float m = pmax[(size_t)v * NR + r];
    float s = psum[(size_t)v * NR + r];
    float nM = fmaxf(M, m);
    S = S * __expf(M - nM) + s * __expf(m - nM);
    M = nM;
  }
  lm[g][rl] = M; ls[g][rl] = S;
  __syncthreads();
  if (threadIdx.x < 64) {
    float M0 = lm[0][rl], S0 = ls[0][rl];
#pragma unroll
    for (int g2 = 1; g2 < 4; ++g2) {
      float m = lm[g2][rl], s2 = ls[g2][rl];
      float nM = fmaxf(M0, m);
      S0 = S0 * __expf(M0 - nM) + s2 * __expf(m - nM);
      M0 = nM;
    }
    lse[r] = M0 + logf(S0);
  }
}

// ---------------- target logit: dot(x[n], W[y[n]]) in f32 (exact) ----------------
__global__ __launch_bounds__(256) void tlogit_kernel(const float* __restrict__ x,
                                                     const int* __restrict__ y,
                                                     const float* __restrict__ W,
                                                     float* __restrict__ tl) {
  const int row = blockIdx.x * 4 + (threadIdx.x >> 6);
  const int l = threadIdx.x & 63;
  const int t = y[row];
  const float4* xr = reinterpret_cast<const float4*>(x + (size_t)row * HD);
  const float4* wr = reinterpret_cast<const float4*>(W + (size_t)t * HD);
  float s = 0.0f;
#pragma unroll
  for (int i = 0; i < HD / 4 / 64; ++i) {
    float4 a = xr[l + i * 64];
    float4 b = wr[l + i * 64];
    s += a.x * b.x + a.y * b.y + a.z * b.z + a.w * b.w;
  }
#pragma unroll
  for (int d = 1; d < 64; d <<= 1) s += __shfl_xor(s, d);
  if (l == 0) tl[row] = s;
}

// ---------------- mean(lse - tlogit) ----------------
__global__ __launch_bounds__(256) void finalize_kernel(const float* __restrict__ lse,
                                                       const float* __restrict__ tl,
                                                       float* __restrict__ out) {
  __shared__ float red[256];
  float s = 0.0f;
  for (int i = threadIdx.x; i < NR; i += 256) s += lse[i] - tl[i];
  red[threadIdx.x] = s;
  __syncthreads();
  for (int d = 128; d > 0; d >>= 1) {
    if ((int)threadIdx.x < d) red[threadIdx.x] += red[threadIdx.x + d];
    __syncthreads();
  }
  if (threadIdx.x == 0) out[0] = red[0] * (1.0f / NR);
}

extern "C" void kernel_launch(void* const* d_in, const int* in_sizes, int n_in,
                              void* d_out, int out_size, void* d_ws, size_t ws_size,
                              hipStream_t stream) {
  const float* x = (const float*)d_in[0];
  const int* y = (const int*)d_in[1];
  const float* W = (const float*)d_in[2];
  float* out = (float*)d_out;
  char* ws = (char*)d_ws;

  if (ws_size >= NEED_NEW) {
    u8* x8      = (u8*)(ws + OFF_X8);
    u8* w8      = (u8*)(ws + OFF_W8);
    float* pmax = (float*)(ws + OFF_PMX);
    float* psum = (float*)(ws + OFF_PSM);
    float* lse  = (float*)(ws + OFF_LSE);
    float* tl   = (float*)(ws + OFF_TL);
    cvt_x8_kernel<<<NR * HD / 16 / 256, 256, 0, stream>>>(x, x8);
    cvt_w8_kernel<<<2048, 256, 0, stream>>>(W, w8);
    gemm8<<<NMB8 * NVB8, 512, 0, stream>>>(x8, w8, pmax, psum);
    row_lse_kernel<<<NR / 64, 256, 0, stream>>>(pmax, psum, lse, NVB8);
    tlogit_kernel<<<NR / 4, 256, 0, stream>>>(x, y, W, tl);
    finalize_kernel<<<1, 256, 0, stream>>>(lse, tl, out);
  } else {
    u16* xb     = (u16*)(ws + FB_XB);
    float* pmax = (float*)(ws + FB_PMAX);
    float* psum = (float*)(ws + FB_PSUM);
    float* lse  = (float*)(ws + FB_LSE);
    float* tl   = (float*)(ws + FB_TL);
    cvt_x_kernel<<<NR * HD / 4 / 256, 256, 0, stream>>>(x, xb);
    gemm_partials_fb<<<NMBF * NVBF, 256, 0, stream>>>(xb, W, pmax, psum);
    row_lse_kernel<<<NR / 64, 256, 0, stream>>>(pmax, psum, lse, NVBF);
    tlogit_kernel<<<NR / 4, 256, 0, stream>>>(x, y, W, tl);
    finalize_kernel<<<1, 256, 0, stream>>>(lse, tl, out);
  }
}